// Round 6
// baseline (4117.112 us; speedup 1.0000x reference)
//
#include <hip/hip_runtime.h>
#include <hip/hip_bf16.h>

#define EMBED 128
#define STATE 64
#define HID   160
#define VOCAB 32000
#define BDIM  32
#define TDIM  512
#define TDEC  128

__device__ inline float softplus_f(float x) { return x > 20.f ? x : log1pf(expf(x)); }
__device__ inline float sigmoid_f(float x) { return 1.f / (1.f + expf(-x)); }

// ---- int64-staging detector (proven no-op for int32; kept for robustness) ----
__global__ void detect_kernel(const int* __restrict__ x, const int* __restrict__ lengths,
                              const int* __restrict__ resp, int* __restrict__ flags) {
    if (threadIdx.x == 0 && blockIdx.x == 0) {
        int f = 1;
        for (int i = 0; i < 32; i++) if (x[2 * i + 1] != 0) { f = 0; break; }
        flags[0] = f;
        f = 1;
        for (int i = 0; i < 16; i++) if (lengths[2 * i + 1] != 0) { f = 0; break; }
        flags[1] = f;
        f = 1;
        for (int i = 0; i < 32; i++) if (resp[2 * i + 1] != 0) { f = 0; break; }
        flags[2] = f;
    }
}

// ---------------- embedding lookup ----------------
__global__ void embed_kernel(const int* __restrict__ tok, const float* __restrict__ table,
                             float* __restrict__ out, int total,
                             const int* __restrict__ flags, int fidx) {
    int mode = flags[fidx];
    int i = blockIdx.x * blockDim.x + threadIdx.x;
    int stride = gridDim.x * blockDim.x;
    for (; i < total; i += stride) {
        int r = i >> 7, e = i & 127;
        int t = mode ? tok[2 * r] : tok[r];
        out[i] = table[(long)t * EMBED + e];
    }
}

// ---------------- row layernorm over 128 elems ----------------
__global__ void ln_kernel(const float* __restrict__ in, const float* __restrict__ g,
                          const float* __restrict__ b, float* __restrict__ out) {
    int r = blockIdx.x, t = threadIdx.x;   // 128 threads
    __shared__ float s1[128];
    float v = in[(long)r * 128 + t];
    s1[t] = v; __syncthreads();
    for (int off = 64; off > 0; off >>= 1) { if (t < off) s1[t] += s1[t + off]; __syncthreads(); }
    float mu = s1[0] / 128.f; __syncthreads();
    float d = v - mu;
    s1[t] = d * d; __syncthreads();
    for (int off = 64; off > 0; off >>= 1) { if (t < off) s1[t] += s1[t + off]; __syncthreads(); }
    float var = s1[0] / 128.f;
    out[(long)r * 128 + t] = d * rsqrtf(var + 1e-5f) * g[t] + b[t];
}

// ---------------- brute in-projection ----------------
__global__ void inproj_kernel(const float* __restrict__ xn, const float* __restrict__ iw,
                              const float* __restrict__ ib, float* __restrict__ proj) {
    int r = blockIdx.x, n = threadIdx.x;   // 256 threads
    __shared__ float a[128];
    if (n < 128) a[n] = xn[(long)r * 128 + n];
    __syncthreads();
    float acc = ib[n];
    for (int k = 0; k < 128; k++) acc = fmaf(a[k], iw[n * 128 + k], acc);
    proj[(long)r * 256 + n] = acc;
}

// ---------------- brute z-projections: sdat[r,0:64]=decay,[64:128]=bt,[128:192]=ct ----------------
__global__ void zproj_kernel(const float* __restrict__ proj,
                             const float* __restrict__ dtw, const float* __restrict__ dtb,
                             const float* __restrict__ bw,  const float* __restrict__ bb_,
                             const float* __restrict__ cw,  const float* __restrict__ cb_,
                             const float* __restrict__ alog, float* __restrict__ sdat) {
    int r = blockIdx.x, j = threadIdx.x;   // 192 threads
    __shared__ float z[128];
    if (j < 128) z[j] = proj[(long)r * 256 + 128 + j];
    __syncthreads();
    int sel = j >> 6, n = j & 63;
    const float* W = sel == 0 ? dtw : (sel == 1 ? bw : cw);
    const float* B = sel == 0 ? dtb : (sel == 1 ? bb_ : cb_);
    float acc = B[n];
    for (int k = 0; k < 128; k++) acc = fmaf(z[k], W[n * 128 + k], acc);
    float v;
    if (sel == 0) { float dt = softplus_f(acc) + 1e-4f; v = expf(-expf(alog[n]) * dt); }
    else v = tanhf(acc);
    sdat[(long)r * 192 + j] = v;
}

// ---------------- depthwise conv1d(k=3,same) + tanh, then * d -> mix[:, :128] ----------------
__global__ void conv_kernel(const float* __restrict__ proj, const float* __restrict__ cw,
                            const float* __restrict__ cb, const float* __restrict__ dvec,
                            float* __restrict__ mix, int total) {
    int i = blockIdx.x * blockDim.x + threadIdx.x;
    int stride = gridDim.x * blockDim.x;
    for (; i < total; i += stride) {
        int e = i & 127;
        int r = i >> 7;
        int t = r & (TDIM - 1);
        float x0 = proj[(long)r * 256 + e];
        float xm = (t > 0)        ? proj[(long)(r - 1) * 256 + e] : 0.f;
        float xp = (t < TDIM - 1) ? proj[(long)(r + 1) * 256 + e] : 0.f;
        float v = cw[e * 3 + 0] * xm + cw[e * 3 + 1] * x0 + cw[e * 3 + 2] * xp + cb[e];
        mix[(long)r * 192 + e] = tanhf(v) * dvec[e];
    }
}

// ---------------- SSM scan ----------------
__global__ void scan_kernel(const float* __restrict__ sdat, float* __restrict__ mix) {
    int b = blockIdx.x, s = threadIdx.x;   // 64 threads
    float state = 0.f;
    int base = b * TDIM;
    for (int t = 0; t < TDIM; ++t) {
        const float* row = sdat + (long)(base + t) * 192;
        state = state * row[s] + row[64 + s];
        mix[(long)(base + t) * 192 + 128 + s] = row[128 + s] * state;
    }
}

// ---------------- brute out-projection + residual ----------------
__global__ void outproj_kernel(const float* __restrict__ mix, const float* __restrict__ ow,
                               const float* __restrict__ ob, float* __restrict__ hseq) {
    int r = blockIdx.x, e = threadIdx.x;   // 128 threads
    __shared__ float m[192];
    for (int j = e; j < 192; j += 128) m[j] = mix[(long)r * 192 + j];
    __syncthreads();
    float acc = ob[e];
    for (int k = 0; k < 192; k++) acc = fmaf(m[k], ow[e * 192 + k], acc);
    hseq[(long)r * 128 + e] += acc;   // own element only: safe RMW
}

// ---------------- fused pool+LN+shared+relu+heads+dec_init; one block per batch ----------------
__global__ void heads_kernel(const float* __restrict__ hseq, const int* __restrict__ lengths,
                             const int* __restrict__ flags,
                             const float* __restrict__ pg, const float* __restrict__ pb,
                             const float* __restrict__ sw, const float* __restrict__ sb,
                             const float* __restrict__ iw_, const float* __restrict__ ib_,
                             const float* __restrict__ stw, const float* __restrict__ stb,
                             const float* __restrict__ cw_, const float* __restrict__ cb2,
                             const float* __restrict__ ow_, const float* __restrict__ ob2,
                             const float* __restrict__ diw, const float* __restrict__ dib,
                             float* __restrict__ o_intent, float* __restrict__ o_style,
                             float* __restrict__ o_cap, float* __restrict__ o_op,
                             float* __restrict__ o_h, float* __restrict__ h0) {
    int b = blockIdx.x;      // 32 blocks
    int t = threadIdx.x;     // 160 threads
    __shared__ float pooled[128], hsh[128], red[128];
    int lm = flags[1];
    int len = lm ? lengths[2 * b] : lengths[b];
    if (t < 128) {
        float s = 0.f;
        for (int tt = 0; tt < len; ++tt) s += hseq[((long)b * TDIM + tt) * 128 + t];
        pooled[t] = s / (float)(len > 1 ? len : 1);
    }
    __syncthreads();
    if (t < 128) red[t] = pooled[t];
    __syncthreads();
    for (int off = 64; off > 0; off >>= 1) { if (t < off) red[t] += red[t + off]; __syncthreads(); }
    float mu = red[0] / 128.f; __syncthreads();
    if (t < 128) { float d = pooled[t] - mu; red[t] = d * d; }
    __syncthreads();
    for (int off = 64; off > 0; off >>= 1) { if (t < off) red[t] += red[t + off]; __syncthreads(); }
    float rstd = rsqrtf(red[0] / 128.f + 1e-5f);
    __syncthreads();
    if (t < 128) pooled[t] = (pooled[t] - mu) * rstd * pg[t] + pb[t];
    __syncthreads();
    if (t < 128) {
        float acc = sb[t];
        for (int k = 0; k < 128; k++) acc = fmaf(pooled[k], sw[t * 128 + k], acc);
        acc = fmaxf(acc, 0.f);
        hsh[t] = acc;
        o_h[b * 128 + t] = acc;
    }
    __syncthreads();
    if (t < 32) {
        float a = ib_[t];
        for (int k = 0; k < 128; k++) a = fmaf(hsh[k], iw_[t * 128 + k], a);
        o_intent[b * 32 + t] = a;
    } else if (t < 40) {
        int n = t - 32; float a = stb[n];
        for (int k = 0; k < 128; k++) a = fmaf(hsh[k], stw[n * 128 + k], a);
        o_style[b * 8 + n] = a;
    } else if (t < 56) {
        int n = t - 40; float a = cb2[n];
        for (int k = 0; k < 128; k++) a = fmaf(hsh[k], cw_[n * 128 + k], a);
        o_cap[b * 16 + n] = a;
    } else if (t < 80) {
        int n = t - 56; float a = ob2[n];
        for (int k = 0; k < 128; k++) a = fmaf(hsh[k], ow_[n * 128 + k], a);
        o_op[b * 24 + n] = a;
    }
    // dec_init: all 160 threads
    {
        float a = dib[t];
        for (int k = 0; k < 128; k++) a = fmaf(hsh[k], diw[t * 128 + k], a);
        h0[b * 160 + t] = tanhf(a);
    }
}

// ---------------- brute gx ----------------
__global__ void gx_kernel(const float* __restrict__ dec_in, const float* __restrict__ wih,
                          const float* __restrict__ bih, float* __restrict__ gx) {
    int r = blockIdx.x, n = threadIdx.x;   // 480 threads
    __shared__ float a[128];
    if (n < 128) a[n] = dec_in[(long)r * 128 + n];
    __syncthreads();
    float acc = bih[n];
    for (int k = 0; k < 128; k++) acc = fmaf(a[k], wih[n * 128 + k], acc);
    gx[(long)r * 480 + n] = acc;
}

// ---------------- GRU decoder ----------------
__launch_bounds__(512)
__global__ void gru_kernel(const float* __restrict__ gx, const float* __restrict__ h0,
                           const float* __restrict__ whh, const float* __restrict__ bhh,
                           float* __restrict__ dec_out) {
    int b = blockIdx.x, tid = threadIdx.x;   // 512 threads
    __shared__ float hs[160];
    __shared__ float gh[480];
    if (tid < 160) hs[tid] = h0[b * 160 + tid];
    __syncthreads();
    for (int t = 0; t < TDEC; ++t) {
        if (tid < 480) {
            float acc = bhh[tid];
            const float4* wv = reinterpret_cast<const float4*>(whh + tid * 160);
            #pragma unroll
            for (int q = 0; q < 40; q++) {
                float4 f = wv[q];
                acc = fmaf(hs[q * 4 + 0], f.x, acc);
                acc = fmaf(hs[q * 4 + 1], f.y, acc);
                acc = fmaf(hs[q * 4 + 2], f.z, acc);
                acc = fmaf(hs[q * 4 + 3], f.w, acc);
            }
            gh[tid] = acc;
        }
        __syncthreads();
        if (tid < 160) {
            const float* gxt = gx + ((long)b * TDEC + t) * 480;
            float r = sigmoid_f(gxt[tid] + gh[tid]);
            float z = sigmoid_f(gxt[160 + tid] + gh[160 + tid]);
            float n = tanhf(gxt[320 + tid] + r * gh[320 + tid]);
            float hnew = (1.f - z) * n + z * hs[tid];
            dec_out[((long)b * TDEC + t) * 160 + tid] = hnew;
            hs[tid] = hnew;
        }
        __syncthreads();
    }
}

// ---------------- tiled GEMM (vocab): C[M,N] = A[M,K] @ W[N,K]^T + bias -> f32 ----------------
__launch_bounds__(256)
__global__ void gemm_kernel(const float* __restrict__ A, int lda,
                            const float* __restrict__ W,
                            const float* __restrict__ bias,
                            float* Cf, int ldc,
                            int M, int N, int K) {
    __shared__ float As[64][17];
    __shared__ float Ws[64][17];
    int m0 = blockIdx.x * 64, n0 = blockIdx.y * 64;
    int tid = threadIdx.x;
    int tr = tid >> 4, tc = tid & 15;
    float acc[4][4];
    #pragma unroll
    for (int i = 0; i < 4; i++)
        #pragma unroll
        for (int j = 0; j < 4; j++) acc[i][j] = 0.f;

    for (int k0 = 0; k0 < K; k0 += 16) {
        for (int idx = tid; idx < 1024; idx += 256) {
            int m = idx >> 4, k = idx & 15;
            int gm = m0 + m;
            As[m][k] = (gm < M) ? A[(long)gm * lda + k0 + k] : 0.f;
        }
        for (int idx = tid; idx < 1024; idx += 256) {
            int n = idx >> 4, k = idx & 15;
            int gn = n0 + n;
            Ws[n][k] = (gn < N) ? W[(long)gn * K + k0 + k] : 0.f;
        }
        __syncthreads();
        #pragma unroll
        for (int kk = 0; kk < 16; ++kk) {
            float a[4], wv[4];
            #pragma unroll
            for (int i = 0; i < 4; i++) a[i] = As[tr * 4 + i][kk];
            #pragma unroll
            for (int j = 0; j < 4; j++) wv[j] = Ws[tc * 4 + j][kk];
            #pragma unroll
            for (int i = 0; i < 4; i++)
                #pragma unroll
                for (int j = 0; j < 4; j++)
                    acc[i][j] = fmaf(a[i], wv[j], acc[i][j]);
        }
        __syncthreads();
    }

    #pragma unroll
    for (int i = 0; i < 4; i++) {
        int m = m0 + tr * 4 + i;
        if (m >= M) continue;
        #pragma unroll
        for (int j = 0; j < 4; j++) {
            int n = n0 + tc * 4 + j;
            if (n >= N) continue;
            Cf[(long)m * ldc + n] = acc[i][j] + bias[n];
        }
    }
}

extern "C" void kernel_launch(void* const* d_in, const int* in_sizes, int n_in,
                              void* d_out, int out_size, void* d_ws, size_t ws_size,
                              hipStream_t stream) {
    const int* x        = (const int*)d_in[0];
    const int* lengths  = (const int*)d_in[1];
    const int* resp_in  = (const int*)d_in[2];
    const float* emb_table = (const float*)d_in[3];
    const float* m_norm_g  = (const float*)d_in[4];
    const float* m_norm_b  = (const float*)d_in[5];
    const float* m_in_w    = (const float*)d_in[6];
    const float* m_in_b    = (const float*)d_in[7];
    const float* m_conv_w  = (const float*)d_in[8];
    const float* m_conv_b  = (const float*)d_in[9];
    const float* m_dt_w    = (const float*)d_in[10];
    const float* m_dt_b    = (const float*)d_in[11];
    const float* m_b_w     = (const float*)d_in[12];
    const float* m_b_b     = (const float*)d_in[13];
    const float* m_c_w     = (const float*)d_in[14];
    const float* m_c_b     = (const float*)d_in[15];
    const float* m_a_log   = (const float*)d_in[16];
    const float* m_d       = (const float*)d_in[17];
    const float* m_out_w   = (const float*)d_in[18];
    const float* m_out_b   = (const float*)d_in[19];
    const float* pool_g    = (const float*)d_in[20];
    const float* pool_b    = (const float*)d_in[21];
    const float* shared_w  = (const float*)d_in[22];
    const float* shared_b  = (const float*)d_in[23];
    const float* intent_w  = (const float*)d_in[24];
    const float* intent_b  = (const float*)d_in[25];
    const float* style_w   = (const float*)d_in[26];
    const float* style_b   = (const float*)d_in[27];
    const float* cap_w     = (const float*)d_in[28];
    const float* cap_b     = (const float*)d_in[29];
    const float* op_w      = (const float*)d_in[30];
    const float* op_b      = (const float*)d_in[31];
    const float* dec_emb   = (const float*)d_in[32];
    const float* dec_init_w = (const float*)d_in[33];
    const float* dec_init_b = (const float*)d_in[34];
    const float* gru_w_ih  = (const float*)d_in[35];
    const float* gru_w_hh  = (const float*)d_in[36];
    const float* gru_b_ih  = (const float*)d_in[37];
    const float* gru_b_hh  = (const float*)d_in[38];
    const float* dec_out_w = (const float*)d_in[39];
    const float* dec_out_b = (const float*)d_in[40];

    // *** reference outputs are float32 (pure-f32 JAX reference) -> d_out is float* ***
    float* out = (float*)d_out;
    const long o_intent = 0;
    const long o_style  = 32 * 32;
    const long o_cap    = o_style + 32 * 8;
    const long o_op     = o_cap + 32 * 16;
    const long o_logits = o_op + 32 * 24;
    const long o_h      = o_logits + (long)BDIM * TDEC * VOCAB;

    const int R = BDIM * TDIM;                 // 16384

    // large scratch inside the d_out logits region (131.07M f32 capacity, we use 14.7M);
    // the vocab GEMM is the final dispatch, reads only dec_o (d_ws) + weights,
    // and fully overwrites this region.
    float* S = out + o_logits;
    float* xn    = S;             S += R * 128;      // also dec_in [4096,128]
    float* proj  = S;             S += R * 256;      // also gx [4096,480]
    float* sdat  = S;             S += R * 192;
    float* hseq  = S;             S += R * 128;
    float* mix   = S;             S += R * 192;

    // small scratch in d_ws (~2.7 MB)
    int* flags   = (int*)d_ws;                       // 16 ints
    float* wsf   = (float*)d_ws + 16;
    float* h0    = wsf;           wsf += 32 * 160;
    float* dec_o = wsf;           wsf += BDIM * TDEC * HID;  // outside logits region

    detect_kernel<<<1, 64, 0, stream>>>(x, lengths, resp_in, flags);

    // ---- encoder ----
    embed_kernel<<<4096, 256, 0, stream>>>(x, emb_table, hseq, R * 128, flags, 0);

    for (int i = 0; i < 2; ++i) {
        ln_kernel<<<R, 128, 0, stream>>>(hseq, m_norm_g + i * 128, m_norm_b + i * 128, xn);
        inproj_kernel<<<R, 256, 0, stream>>>(xn, m_in_w + i * 256 * 128, m_in_b + i * 256, proj);
        conv_kernel<<<8192, 256, 0, stream>>>(proj, m_conv_w + i * 384, m_conv_b + i * 128,
                                              m_d + i * 128, mix, R * 128);
        zproj_kernel<<<R, 192, 0, stream>>>(proj,
            m_dt_w + i * 8192, m_dt_b + i * 64,
            m_b_w + i * 8192,  m_b_b + i * 64,
            m_c_w + i * 8192,  m_c_b + i * 64,
            m_a_log + i * 64, sdat);
        scan_kernel<<<BDIM, 64, 0, stream>>>(sdat, mix);
        outproj_kernel<<<R, 128, 0, stream>>>(mix, m_out_w + i * 128 * 192, m_out_b + i * 128, hseq);
    }

    // ---- fused pooled heads + dec_init ----
    heads_kernel<<<BDIM, 160, 0, stream>>>(hseq, lengths, flags,
        pool_g, pool_b, shared_w, shared_b,
        intent_w, intent_b, style_w, style_b, cap_w, cap_b, op_w, op_b,
        dec_init_w, dec_init_b,
        out + o_intent, out + o_style, out + o_cap, out + o_op, out + o_h, h0);

    // ---- decoder ----
    const int Rd = BDIM * TDEC;    // 4096
    float* dec_in = xn;            // alias (encoder use finished)
    float* gx = proj;              // alias
    embed_kernel<<<2048, 256, 0, stream>>>(resp_in, dec_emb, dec_in, Rd * 128, flags, 2);
    gx_kernel<<<Rd, 480, 0, stream>>>(dec_in, gru_w_ih, gru_b_ih, gx);
    gru_kernel<<<BDIM, 512, 0, stream>>>(gx, h0, gru_w_hh, gru_b_hh, dec_o);

    // ---- vocab projection: final dispatch, overwrites the d_out scratch region ----
    gemm_kernel<<<dim3((Rd + 63) / 64, (VOCAB + 63) / 64), 256, 0, stream>>>(
        dec_o, 160, dec_out_w, dec_out_b, out + o_logits, VOCAB, Rd, VOCAB, 160);
}

// Round 7
// 1013.690 us; speedup vs baseline: 4.0615x; 4.0615x over previous
//
#include <hip/hip_runtime.h>
#include <hip/hip_bf16.h>

#define EMBED 128
#define STATE 64
#define HID   160
#define VOCAB 32000
#define BDIM  32
#define TDIM  512
#define TDEC  128

typedef __attribute__((ext_vector_type(4))) float f32x4;
typedef __attribute__((ext_vector_type(8))) short bf16x8;

__device__ inline float softplus_f(float x) { return x > 20.f ? x : log1pf(expf(x)); }
__device__ inline float sigmoid_f(float x) { return 1.f / (1.f + expf(-x)); }
__device__ inline short f2bf(float x) {
    __hip_bfloat16 v = __float2bfloat16(x);
    return *reinterpret_cast<short*>(&v);
}

// ---- int64-staging detector (proven no-op for int32; kept for robustness) ----
__global__ void detect_kernel(const int* __restrict__ x, const int* __restrict__ lengths,
                              const int* __restrict__ resp, int* __restrict__ flags) {
    if (threadIdx.x == 0 && blockIdx.x == 0) {
        int f = 1;
        for (int i = 0; i < 32; i++) if (x[2 * i + 1] != 0) { f = 0; break; }
        flags[0] = f;
        f = 1;
        for (int i = 0; i < 16; i++) if (lengths[2 * i + 1] != 0) { f = 0; break; }
        flags[1] = f;
        f = 1;
        for (int i = 0; i < 32; i++) if (resp[2 * i + 1] != 0) { f = 0; break; }
        flags[2] = f;
    }
}

// ---------------- embedding lookup ----------------
__global__ void embed_kernel(const int* __restrict__ tok, const float* __restrict__ table,
                             float* __restrict__ out, int total,
                             const int* __restrict__ flags, int fidx) {
    int mode = flags[fidx];
    int i = blockIdx.x * blockDim.x + threadIdx.x;
    int stride = gridDim.x * blockDim.x;
    for (; i < total; i += stride) {
        int r = i >> 7, e = i & 127;
        int t = mode ? tok[2 * r] : tok[r];
        out[i] = table[(long)t * EMBED + e];
    }
}

// ---------------- row layernorm over 128 elems ----------------
__global__ void ln_kernel(const float* __restrict__ in, const float* __restrict__ g,
                          const float* __restrict__ b, float* __restrict__ out) {
    int r = blockIdx.x, t = threadIdx.x;   // 128 threads
    __shared__ float s1[128];
    float v = in[(long)r * 128 + t];
    s1[t] = v; __syncthreads();
    for (int off = 64; off > 0; off >>= 1) { if (t < off) s1[t] += s1[t + off]; __syncthreads(); }
    float mu = s1[0] / 128.f; __syncthreads();
    float d = v - mu;
    s1[t] = d * d; __syncthreads();
    for (int off = 64; off > 0; off >>= 1) { if (t < off) s1[t] += s1[t + off]; __syncthreads(); }
    float var = s1[0] / 128.f;
    out[(long)r * 128 + t] = d * rsqrtf(var + 1e-5f) * g[t] + b[t];
}

// ---------------- depthwise conv1d(k=3,same) + tanh, then * d -> mix[:, :128] ----------------
__global__ void conv_kernel(const float* __restrict__ proj, const float* __restrict__ cw,
                            const float* __restrict__ cb, const float* __restrict__ dvec,
                            float* __restrict__ mix, int total) {
    int i = blockIdx.x * blockDim.x + threadIdx.x;
    int stride = gridDim.x * blockDim.x;
    for (; i < total; i += stride) {
        int e = i & 127;
        int r = i >> 7;
        int t = r & (TDIM - 1);
        float x0 = proj[(long)r * 256 + e];
        float xm = (t > 0)        ? proj[(long)(r - 1) * 256 + e] : 0.f;
        float xp = (t < TDIM - 1) ? proj[(long)(r + 1) * 256 + e] : 0.f;
        float v = cw[e * 3 + 0] * xm + cw[e * 3 + 1] * x0 + cw[e * 3 + 2] * xp + cb[e];
        mix[(long)r * 192 + e] = tanhf(v) * dvec[e];
    }
}

// ---------------- SSM scan over sdat[r,0:64]=decay,[64:128]=bt,[128:192]=ct ----------------
__global__ void scan_kernel(const float* __restrict__ sdat, float* __restrict__ mix) {
    int b = blockIdx.x, s = threadIdx.x;   // 64 threads
    float state = 0.f;
    int base = b * TDIM;
    #pragma unroll 4
    for (int t = 0; t < TDIM; ++t) {
        const float* row = sdat + (long)(base + t) * 192;
        state = state * row[s] + row[64 + s];
        mix[(long)(base + t) * 192 + 128 + s] = row[128 + s] * state;
    }
}

// ---------------- fused pool+LN+shared+relu+heads+dec_init; one block per batch ----------------
__global__ void heads_kernel(const float* __restrict__ hseq, const int* __restrict__ lengths,
                             const int* __restrict__ flags,
                             const float* __restrict__ pg, const float* __restrict__ pb,
                             const float* __restrict__ sw, const float* __restrict__ sb,
                             const float* __restrict__ iw_, const float* __restrict__ ib_,
                             const float* __restrict__ stw, const float* __restrict__ stb,
                             const float* __restrict__ cw_, const float* __restrict__ cb2,
                             const float* __restrict__ ow_, const float* __restrict__ ob2,
                             const float* __restrict__ diw, const float* __restrict__ dib,
                             float* __restrict__ o_intent, float* __restrict__ o_style,
                             float* __restrict__ o_cap, float* __restrict__ o_op,
                             float* __restrict__ o_h, float* __restrict__ h0) {
    int b = blockIdx.x;      // 32 blocks
    int t = threadIdx.x;     // 160 threads
    __shared__ float pooled[128], hsh[128], red[128];
    int lm = flags[1];
    int len = lm ? lengths[2 * b] : lengths[b];
    if (t < 128) {
        float s = 0.f;
        for (int tt = 0; tt < len; ++tt) s += hseq[((long)b * TDIM + tt) * 128 + t];
        pooled[t] = s / (float)(len > 1 ? len : 1);
    }
    __syncthreads();
    if (t < 128) red[t] = pooled[t];
    __syncthreads();
    for (int off = 64; off > 0; off >>= 1) { if (t < off) red[t] += red[t + off]; __syncthreads(); }
    float mu = red[0] / 128.f; __syncthreads();
    if (t < 128) { float d = pooled[t] - mu; red[t] = d * d; }
    __syncthreads();
    for (int off = 64; off > 0; off >>= 1) { if (t < off) red[t] += red[t + off]; __syncthreads(); }
    float rstd = rsqrtf(red[0] / 128.f + 1e-5f);
    __syncthreads();
    if (t < 128) pooled[t] = (pooled[t] - mu) * rstd * pg[t] + pb[t];
    __syncthreads();
    if (t < 128) {
        float acc = sb[t];
        for (int k = 0; k < 128; k++) acc = fmaf(pooled[k], sw[t * 128 + k], acc);
        acc = fmaxf(acc, 0.f);
        hsh[t] = acc;
        o_h[b * 128 + t] = acc;
    }
    __syncthreads();
    if (t < 32) {
        float a = ib_[t];
        for (int k = 0; k < 128; k++) a = fmaf(hsh[k], iw_[t * 128 + k], a);
        o_intent[b * 32 + t] = a;
    } else if (t < 40) {
        int n = t - 32; float a = stb[n];
        for (int k = 0; k < 128; k++) a = fmaf(hsh[k], stw[n * 128 + k], a);
        o_style[b * 8 + n] = a;
    } else if (t < 56) {
        int n = t - 40; float a = cb2[n];
        for (int k = 0; k < 128; k++) a = fmaf(hsh[k], cw_[n * 128 + k], a);
        o_cap[b * 16 + n] = a;
    } else if (t < 80) {
        int n = t - 56; float a = ob2[n];
        for (int k = 0; k < 128; k++) a = fmaf(hsh[k], ow_[n * 128 + k], a);
        o_op[b * 24 + n] = a;
    }
    {
        float a = dib[t];
        for (int k = 0; k < 128; k++) a = fmaf(hsh[k], diw[t * 128 + k], a);
        h0[b * 160 + t] = tanhf(a);
    }
}

// ---------------- tiled f32 GEMM with fused epilogues (encoder/decoder small GEMMs) ----------------
// epi: 0=none 1=relu 2=tanh 3=softplus->decay(alog)
__launch_bounds__(256)
__global__ void gemm_f32(const float* __restrict__ A, int lda,
                         const float* __restrict__ W,
                         const float* __restrict__ bias,
                         const float* __restrict__ res, int ldres,
                         float* __restrict__ Cf, int ldc,
                         int M, int N, int K, int epi,
                         const float* __restrict__ alog) {
    __shared__ float As[64][17];
    __shared__ float Ws[64][17];
    int m0 = blockIdx.x * 64, n0 = blockIdx.y * 64;
    int tid = threadIdx.x;
    int tr = tid >> 4, tc = tid & 15;
    float acc[4][4];
    #pragma unroll
    for (int i = 0; i < 4; i++)
        #pragma unroll
        for (int j = 0; j < 4; j++) acc[i][j] = 0.f;

    for (int k0 = 0; k0 < K; k0 += 16) {
        for (int idx = tid; idx < 1024; idx += 256) {
            int m = idx >> 4, k = idx & 15;
            int gm = m0 + m;
            As[m][k] = (gm < M) ? A[(long)gm * lda + k0 + k] : 0.f;
        }
        for (int idx = tid; idx < 1024; idx += 256) {
            int n = idx >> 4, k = idx & 15;
            int gn = n0 + n;
            Ws[n][k] = (gn < N) ? W[(long)gn * K + k0 + k] : 0.f;
        }
        __syncthreads();
        #pragma unroll
        for (int kk = 0; kk < 16; ++kk) {
            float a[4], wv[4];
            #pragma unroll
            for (int i = 0; i < 4; i++) a[i] = As[tr * 4 + i][kk];
            #pragma unroll
            for (int j = 0; j < 4; j++) wv[j] = Ws[tc * 4 + j][kk];
            #pragma unroll
            for (int i = 0; i < 4; i++)
                #pragma unroll
                for (int j = 0; j < 4; j++)
                    acc[i][j] = fmaf(a[i], wv[j], acc[i][j]);
        }
        __syncthreads();
    }

    #pragma unroll
    for (int i = 0; i < 4; i++) {
        int m = m0 + tr * 4 + i;
        if (m >= M) continue;
        #pragma unroll
        for (int j = 0; j < 4; j++) {
            int n = n0 + tc * 4 + j;
            if (n >= N) continue;
            float v = acc[i][j] + (bias ? bias[n] : 0.f);
            if (epi == 1) v = fmaxf(v, 0.f);
            else if (epi == 2) v = tanhf(v);
            else if (epi == 3) {
                float dt = softplus_f(v) + 1e-4f;
                v = expf(-expf(alog[n]) * dt);
            }
            if (res) v += res[(long)m * ldres + n];
            Cf[(long)m * ldc + n] = v;
        }
    }
}

// ---------------- GRU decoder: w_hh rows held in registers; bf16 output ----------------
__launch_bounds__(512, 1)
__global__ void gru_kernel(const float* __restrict__ gx, const float* __restrict__ h0,
                           const float* __restrict__ whh, const float* __restrict__ bhh,
                           short* __restrict__ dec_out /* bf16 bits [B*TDEC][160] */) {
    int b = blockIdx.x, tid = threadIdx.x;   // 512 threads
    __shared__ float hs[160];
    __shared__ float gh[480];
    f32x4 w[40];
    float bh = 0.f;
    if (tid < 480) {
        bh = bhh[tid];
        const f32x4* wrow = reinterpret_cast<const f32x4*>(whh + tid * 160);
        #pragma unroll
        for (int q = 0; q < 40; q++) w[q] = wrow[q];
    }
    if (tid < 160) hs[tid] = h0[b * 160 + tid];
    __syncthreads();
    for (int t = 0; t < TDEC; ++t) {
        if (tid < 480) {
            float acc = bh;
            const f32x4* hv = reinterpret_cast<const f32x4*>(hs);
            #pragma unroll
            for (int q = 0; q < 40; q++) {
                f32x4 h4 = hv[q];
                acc = fmaf(h4.x, w[q].x, acc);
                acc = fmaf(h4.y, w[q].y, acc);
                acc = fmaf(h4.z, w[q].z, acc);
                acc = fmaf(h4.w, w[q].w, acc);
            }
            gh[tid] = acc;
        }
        __syncthreads();
        if (tid < 160) {
            const float* gxt = gx + ((long)b * TDEC + t) * 480;
            float r = sigmoid_f(gxt[tid] + gh[tid]);
            float z = sigmoid_f(gxt[160 + tid] + gh[160 + tid]);
            float n = tanhf(gxt[320 + tid] + r * gh[320 + tid]);
            float hnew = (1.f - z) * n + z * hs[tid];
            dec_out[((long)b * TDEC + t) * 160 + tid] = f2bf(hnew);
            hs[tid] = hnew;
        }
        __syncthreads();
    }
}

// ---------------- f32 -> bf16 bits cast ----------------
__global__ void castbf_kernel(const float* __restrict__ in, short* __restrict__ out, int n) {
    int i = blockIdx.x * blockDim.x + threadIdx.x;
    int stride = gridDim.x * blockDim.x;
    for (; i < n; i += stride) out[i] = f2bf(in[i]);
}

// ---------------- vocab projection: bf16 MFMA GEMM, C[M,N] = A[M,160] @ W[N,160]^T + bias ----------------
// BM=128, BN=64. grid = (N/64, M/128). 256 threads = 4 waves (2x2).
__launch_bounds__(256)
__global__ void vocab_gemm(const short* __restrict__ A,   // [4096][160] bf16 bits
                           const short* __restrict__ W,   // [32000][160] bf16 bits
                           const float* __restrict__ bias,
                           float* __restrict__ C) {
    __shared__ short As[128][168];   // +8 pad: 336B row stride -> <=2-way bank alias
    __shared__ short Ws[64][168];
    int n0 = blockIdx.x * 64, m0 = blockIdx.y * 128;
    int tid = threadIdx.x;

    // stage A tile: 128 rows x 20 chunks(8 bf16) = 2560 chunks; 10 per thread
    #pragma unroll
    for (int it = 0; it < 10; ++it) {
        int idx = tid + it * 256;
        int r = idx / 20, c8 = idx % 20;
        *(bf16x8*)&As[r][c8 * 8] = *(const bf16x8*)&A[(long)(m0 + r) * 160 + c8 * 8];
    }
    // stage W tile: 64 rows x 20 chunks = 1280 chunks; 5 per thread
    #pragma unroll
    for (int it = 0; it < 5; ++it) {
        int idx = tid + it * 256;
        int r = idx / 20, c8 = idx % 20;
        *(bf16x8*)&Ws[r][c8 * 8] = *(const bf16x8*)&W[(long)(n0 + r) * 160 + c8 * 8];
    }
    __syncthreads();

    int wave = tid >> 6, lane = tid & 63;
    int wm = wave >> 1, wn = wave & 1;     // wave covers rows wm*64..+63, cols wn*32..+31
    int fr = lane & 15;                    // fragment row/col within 16
    int kg = lane >> 4;                    // k-group 0..3 -> k offset kg*8

    f32x4 acc[4][2];
    #pragma unroll
    for (int i = 0; i < 4; i++)
        #pragma unroll
        for (int j = 0; j < 2; j++) acc[i][j] = (f32x4){0.f, 0.f, 0.f, 0.f};

    #pragma unroll
    for (int ks = 0; ks < 5; ++ks) {       // K = 5 * 32
        int kb = ks * 32 + kg * 8;
        bf16x8 a[4], bfr[2];
        #pragma unroll
        for (int i = 0; i < 4; i++)
            a[i] = *(const bf16x8*)&As[wm * 64 + i * 16 + fr][kb];
        #pragma unroll
        for (int j = 0; j < 2; j++)
            bfr[j] = *(const bf16x8*)&Ws[wn * 32 + j * 16 + fr][kb];
        #pragma unroll
        for (int i = 0; i < 4; i++)
            #pragma unroll
            for (int j = 0; j < 2; j++)
                acc[i][j] = __builtin_amdgcn_mfma_f32_16x16x32_bf16(a[i], bfr[j], acc[i][j], 0, 0, 0);
    }

    // C/D layout (HW-verified): col = lane&15, row = (lane>>4)*4 + reg
    #pragma unroll
    for (int i = 0; i < 4; i++) {
        #pragma unroll
        for (int j = 0; j < 2; j++) {
            int col = n0 + wn * 32 + j * 16 + fr;
            float bv = bias[col];
            #pragma unroll
            for (int q = 0; q < 4; q++) {
                int row = m0 + wm * 64 + i * 16 + kg * 4 + q;
                C[(long)row * VOCAB + col] = acc[i][j][q] + bv;
            }
        }
    }
}

static inline dim3 gemm_grid(int M, int N) {
    return dim3((M + 63) / 64, (N + 63) / 64);
}

extern "C" void kernel_launch(void* const* d_in, const int* in_sizes, int n_in,
                              void* d_out, int out_size, void* d_ws, size_t ws_size,
                              hipStream_t stream) {
    const int* x        = (const int*)d_in[0];
    const int* lengths  = (const int*)d_in[1];
    const int* resp_in  = (const int*)d_in[2];
    const float* emb_table = (const float*)d_in[3];
    const float* m_norm_g  = (const float*)d_in[4];
    const float* m_norm_b  = (const float*)d_in[5];
    const float* m_in_w    = (const float*)d_in[6];
    const float* m_in_b    = (const float*)d_in[7];
    const float* m_conv_w  = (const float*)d_in[8];
    const float* m_conv_b  = (const float*)d_in[9];
    const float* m_dt_w    = (const float*)d_in[10];
    const float* m_dt_b    = (const float*)d_in[11];
    const float* m_b_w     = (const float*)d_in[12];
    const float* m_b_b     = (const float*)d_in[13];
    const float* m_c_w     = (const float*)d_in[14];
    const float* m_c_b     = (const float*)d_in[15];
    const float* m_a_log   = (const float*)d_in[16];
    const float* m_d       = (const float*)d_in[17];
    const float* m_out_w   = (const float*)d_in[18];
    const float* m_out_b   = (const float*)d_in[19];
    const float* pool_g    = (const float*)d_in[20];
    const float* pool_b    = (const float*)d_in[21];
    const float* shared_w  = (const float*)d_in[22];
    const float* shared_b  = (const float*)d_in[23];
    const float* intent_w  = (const float*)d_in[24];
    const float* intent_b  = (const float*)d_in[25];
    const float* style_w   = (const float*)d_in[26];
    const float* style_b   = (const float*)d_in[27];
    const float* cap_w     = (const float*)d_in[28];
    const float* cap_b     = (const float*)d_in[29];
    const float* op_w      = (const float*)d_in[30];
    const float* op_b      = (const float*)d_in[31];
    const float* dec_emb   = (const float*)d_in[32];
    const float* dec_init_w = (const float*)d_in[33];
    const float* dec_init_b = (const float*)d_in[34];
    const float* gru_w_ih  = (const float*)d_in[35];
    const float* gru_w_hh  = (const float*)d_in[36];
    const float* gru_b_ih  = (const float*)d_in[37];
    const float* gru_b_hh  = (const float*)d_in[38];
    const float* dec_out_w = (const float*)d_in[39];
    const float* dec_out_b = (const float*)d_in[40];

    float* out = (float*)d_out;
    const long o_intent = 0;
    const long o_style  = 32 * 32;
    const long o_cap    = o_style + 32 * 8;
    const long o_op     = o_cap + 32 * 16;
    const long o_logits = o_op + 32 * 24;
    const long o_h      = o_logits + (long)BDIM * TDEC * VOCAB;

    const int R = BDIM * TDIM;                 // 16384

    // large scratch inside the d_out logits region (131.07M f32 capacity; we use 14.7M);
    // vocab_gemm is the final dispatch, reads only d_ws + weights, overwrites this region.
    float* S = out + o_logits;
    float* xn    = S;             S += R * 128;      // also dec_in [4096,128]
    float* proj  = S;             S += R * 256;      // also gx [4096,480]
    float* sdat  = S;             S += R * 192;
    float* hseq  = S;             S += R * 128;
    float* mix   = S;             S += R * 192;

    // d_ws (~11.6 MB): flags | h0 | dec_o(bf16) | W_bf(bf16)
    int* flags   = (int*)d_ws;                        // 16 ints (64 B)
    float* wsf   = (float*)d_ws + 16;
    float* h0    = wsf;           wsf += 32 * 160;    // 20 KB
    short* dec_obf = (short*)wsf;                     // [4096][160] bf16
    short* w_bf  = dec_obf + (long)BDIM * TDEC * HID; // [32000][160] bf16

    detect_kernel<<<1, 64, 0, stream>>>(x, lengths, resp_in, flags);
    // cast vocab weight to bf16 once per call (independent of everything upstream)
    castbf_kernel<<<2048, 256, 0, stream>>>(dec_out_w, w_bf, VOCAB * HID);

    // ---- encoder ----
    embed_kernel<<<4096, 256, 0, stream>>>(x, emb_table, hseq, R * 128, flags, 0);

    for (int i = 0; i < 2; ++i) {
        ln_kernel<<<R, 128, 0, stream>>>(hseq, m_norm_g + i * 128, m_norm_b + i * 128, xn);
        gemm_f32<<<gemm_grid(R, 256), 256, 0, stream>>>(
            xn, 128, m_in_w + i * 256 * 128, m_in_b + i * 256,
            nullptr, 0, proj, 256, R, 256, 128, 0, nullptr);
        conv_kernel<<<8192, 256, 0, stream>>>(proj, m_conv_w + i * 384, m_conv_b + i * 128,
                                              m_d + i * 128, mix, R * 128);
        gemm_f32<<<gemm_grid(R, 64), 256, 0, stream>>>(
            proj + 128, 256, m_dt_w + i * 8192, m_dt_b + i * 64,
            nullptr, 0, sdat, 192, R, 64, 128, 3, m_a_log + i * 64);
        gemm_f32<<<gemm_grid(R, 64), 256, 0, stream>>>(
            proj + 128, 256, m_b_w + i * 8192, m_b_b + i * 64,
            nullptr, 0, sdat + 64, 192, R, 64, 128, 2, nullptr);
        gemm_f32<<<gemm_grid(R, 64), 256, 0, stream>>>(
            proj + 128, 256, m_c_w + i * 8192, m_c_b + i * 64,
            nullptr, 0, sdat + 128, 192, R, 64, 128, 2, nullptr);
        scan_kernel<<<BDIM, 64, 0, stream>>>(sdat, mix);
        // residual add in-place (res == C: each element read only by its writer thread)
        gemm_f32<<<gemm_grid(R, 128), 256, 0, stream>>>(
            mix, 192, m_out_w + i * 128 * 192, m_out_b + i * 128,
            hseq, 128, hseq, 128, R, 128, 192, 0, nullptr);
    }

    // ---- fused pooled heads + dec_init ----
    heads_kernel<<<BDIM, 160, 0, stream>>>(hseq, lengths, flags,
        pool_g, pool_b, shared_w, shared_b,
        intent_w, intent_b, style_w, style_b, cap_w, cap_b, op_w, op_b,
        dec_init_w, dec_init_b,
        out + o_intent, out + o_style, out + o_cap, out + o_op, out + o_h, h0);

    // ---- decoder ----
    const int Rd = BDIM * TDEC;    // 4096
    float* dec_in = xn;            // alias (encoder use finished)
    float* gx = proj;              // alias
    embed_kernel<<<2048, 256, 0, stream>>>(resp_in, dec_emb, dec_in, Rd * 128, flags, 2);
    gemm_f32<<<gemm_grid(Rd, 480), 256, 0, stream>>>(
        dec_in, 128, gru_w_ih, gru_b_ih, nullptr, 0, gx, 480, Rd, 480, 128, 0, nullptr);
    gru_kernel<<<BDIM, 512, 0, stream>>>(gx, h0, gru_w_hh, gru_b_hh, dec_obf);

    // ---- vocab projection: bf16 MFMA, final dispatch, overwrites d_out scratch ----
    vocab_gemm<<<dim3(VOCAB / 64, Rd / 128), 256, 0, stream>>>(
        dec_obf, w_bf, dec_out_b, out + o_logits);
}

// Round 8
// 642.150 us; speedup vs baseline: 6.4114x; 1.5786x over previous
//
#include <hip/hip_runtime.h>
#include <hip/hip_bf16.h>

#define EMBED 128
#define STATE 64
#define HID   160
#define VOCAB 32000
#define BDIM  32
#define TDIM  512
#define TDEC  128

typedef __attribute__((ext_vector_type(4))) float f32x4;
typedef __attribute__((ext_vector_type(8))) short bf16x8;

__device__ inline float softplus_f(float x) { return x > 20.f ? x : log1pf(expf(x)); }
__device__ inline float sigmoid_f(float x) { return 1.f / (1.f + expf(-x)); }
__device__ inline short f2bf(float x) {
    __hip_bfloat16 v = __float2bfloat16(x);
    return *reinterpret_cast<short*>(&v);
}
__device__ inline float bf2f(short u) {
    union { unsigned int i; float f; } cv;
    cv.i = ((unsigned int)(unsigned short)u) << 16;
    return cv.f;
}

// ---- int64-staging detector (proven no-op for int32; kept for robustness) ----
__global__ void detect_kernel(const int* __restrict__ x, const int* __restrict__ lengths,
                              const int* __restrict__ resp, int* __restrict__ flags) {
    if (threadIdx.x == 0 && blockIdx.x == 0) {
        int f = 1;
        for (int i = 0; i < 32; i++) if (x[2 * i + 1] != 0) { f = 0; break; }
        flags[0] = f;
        f = 1;
        for (int i = 0; i < 16; i++) if (lengths[2 * i + 1] != 0) { f = 0; break; }
        flags[1] = f;
        f = 1;
        for (int i = 0; i < 32; i++) if (resp[2 * i + 1] != 0) { f = 0; break; }
        flags[2] = f;
    }
}

// ---------------- embedding lookup: f32 out (encoder residual stream) ----------------
__global__ void embed_kernel(const int* __restrict__ tok, const float* __restrict__ table,
                             float* __restrict__ out, int total,
                             const int* __restrict__ flags, int fidx) {
    int mode = flags[fidx];
    int i = blockIdx.x * blockDim.x + threadIdx.x;
    int stride = gridDim.x * blockDim.x;
    for (; i < total; i += stride) {
        int r = i >> 7, e = i & 127;
        int t = mode ? tok[2 * r] : tok[r];
        out[i] = table[(long)t * EMBED + e];
    }
}

// ---------------- embedding lookup: bf16 out (decoder input) ----------------
__global__ void embed_bf_kernel(const int* __restrict__ tok, const float* __restrict__ table,
                                short* __restrict__ out, int total,
                                const int* __restrict__ flags, int fidx) {
    int mode = flags[fidx];
    int i = blockIdx.x * blockDim.x + threadIdx.x;
    int stride = gridDim.x * blockDim.x;
    for (; i < total; i += stride) {
        int r = i >> 7, e = i & 127;
        int t = mode ? tok[2 * r] : tok[r];
        out[i] = f2bf(table[(long)t * EMBED + e]);
    }
}

// ---------------- row layernorm over 128 elems -> bf16 ----------------
__global__ void ln_kernel(const float* __restrict__ in, const float* __restrict__ g,
                          const float* __restrict__ b, short* __restrict__ out) {
    int r = blockIdx.x, t = threadIdx.x;   // 128 threads
    __shared__ float s1[128];
    float v = in[(long)r * 128 + t];
    s1[t] = v; __syncthreads();
    for (int off = 64; off > 0; off >>= 1) { if (t < off) s1[t] += s1[t + off]; __syncthreads(); }
    float mu = s1[0] / 128.f; __syncthreads();
    float d = v - mu;
    s1[t] = d * d; __syncthreads();
    for (int off = 64; off > 0; off >>= 1) { if (t < off) s1[t] += s1[t + off]; __syncthreads(); }
    float var = s1[0] / 128.f;
    out[(long)r * 128 + t] = f2bf(d * rsqrtf(var + 1e-5f) * g[t] + b[t]);
}

// ---------------- depthwise conv1d(k=3,same) + tanh, * d -> mixb[:, :128] (bf16 in/out) ----------------
__global__ void conv_kernel(const short* __restrict__ projb, const float* __restrict__ cw,
                            const float* __restrict__ cb, const float* __restrict__ dvec,
                            short* __restrict__ mixb, int total) {
    int i = blockIdx.x * blockDim.x + threadIdx.x;
    int stride = gridDim.x * blockDim.x;
    for (; i < total; i += stride) {
        int e = i & 127;
        int r = i >> 7;
        int t = r & (TDIM - 1);
        float x0 = bf2f(projb[(long)r * 256 + e]);
        float xm = (t > 0)        ? bf2f(projb[(long)(r - 1) * 256 + e]) : 0.f;
        float xp = (t < TDIM - 1) ? bf2f(projb[(long)(r + 1) * 256 + e]) : 0.f;
        float v = cw[e * 3 + 0] * xm + cw[e * 3 + 1] * x0 + cw[e * 3 + 2] * xp + cb[e];
        mixb[(long)r * 192 + e] = f2bf(tanhf(v) * dvec[e]);
    }
}

// ---------------- chunked parallel SSM scan: 8 chunks x 64 states per batch ----------------
// sdat[r][0:64]=decay, [64:128]=bt, [128:192]=ct (f32). y -> mixb[:,128:192] (bf16).
__global__ void scan2_kernel(const float* __restrict__ sdat, short* __restrict__ mixb) {
    int b = blockIdx.x;              // 32 blocks
    int tid = threadIdx.x;           // 512 threads
    int c = tid >> 6, s = tid & 63;
    __shared__ float SA[8][64], SB[8][64], SI[8][64];
    long base = (long)b * TDIM;
    int t0 = c * 64;
    float Aacc = 1.f, Bacc = 0.f;
    #pragma unroll 4
    for (int t = t0; t < t0 + 64; ++t) {
        const float* row = sdat + (base + t) * 192;
        float d = row[s], bt = row[64 + s];
        Bacc = Bacc * d + bt;
        Aacc *= d;
    }
    SA[c][s] = Aacc; SB[c][s] = Bacc;
    __syncthreads();
    if (c == 0) {                     // affine combine over 8 chunks (exact same recurrence)
        float st = 0.f;
        #pragma unroll
        for (int cc = 0; cc < 8; ++cc) {
            SI[cc][s] = st;
            st = SB[cc][s] + SA[cc][s] * st;
        }
    }
    __syncthreads();
    float st = SI[c][s];
    #pragma unroll 4
    for (int t = t0; t < t0 + 64; ++t) {
        const float* row = sdat + (base + t) * 192;
        st = st * row[s] + row[64 + s];
        mixb[(base + t) * 192 + 128 + s] = f2bf(row[128 + s] * st);
    }
}

// ---------------- fused pool+LN+shared+relu+heads+dec_init; one block per batch ----------------
__global__ void heads_kernel(const float* __restrict__ hseq, const int* __restrict__ lengths,
                             const int* __restrict__ flags,
                             const float* __restrict__ pg, const float* __restrict__ pb,
                             const float* __restrict__ sw, const float* __restrict__ sb,
                             const float* __restrict__ iw_, const float* __restrict__ ib_,
                             const float* __restrict__ stw, const float* __restrict__ stb,
                             const float* __restrict__ cw_, const float* __restrict__ cb2,
                             const float* __restrict__ ow_, const float* __restrict__ ob2,
                             const float* __restrict__ diw, const float* __restrict__ dib,
                             float* __restrict__ o_intent, float* __restrict__ o_style,
                             float* __restrict__ o_cap, float* __restrict__ o_op,
                             float* __restrict__ o_h, float* __restrict__ h0) {
    int b = blockIdx.x;      // 32 blocks
    int t = threadIdx.x;     // 160 threads
    __shared__ float pooled[128], hsh[128], red[128];
    int lm = flags[1];
    int len = lm ? lengths[2 * b] : lengths[b];
    if (t < 128) {
        float s = 0.f;
        for (int tt = 0; tt < len; ++tt) s += hseq[((long)b * TDIM + tt) * 128 + t];
        pooled[t] = s / (float)(len > 1 ? len : 1);
    }
    __syncthreads();
    if (t < 128) red[t] = pooled[t];
    __syncthreads();
    for (int off = 64; off > 0; off >>= 1) { if (t < off) red[t] += red[t + off]; __syncthreads(); }
    float mu = red[0] / 128.f; __syncthreads();
    if (t < 128) { float d = pooled[t] - mu; red[t] = d * d; }
    __syncthreads();
    for (int off = 64; off > 0; off >>= 1) { if (t < off) red[t] += red[t + off]; __syncthreads(); }
    float rstd = rsqrtf(red[0] / 128.f + 1e-5f);
    __syncthreads();
    if (t < 128) pooled[t] = (pooled[t] - mu) * rstd * pg[t] + pb[t];
    __syncthreads();
    if (t < 128) {
        float acc = sb[t];
        for (int k = 0; k < 128; k++) acc = fmaf(pooled[k], sw[t * 128 + k], acc);
        acc = fmaxf(acc, 0.f);
        hsh[t] = acc;
        o_h[b * 128 + t] = acc;
    }
    __syncthreads();
    if (t < 32) {
        float a = ib_[t];
        for (int k = 0; k < 128; k++) a = fmaf(hsh[k], iw_[t * 128 + k], a);
        o_intent[b * 32 + t] = a;
    } else if (t < 40) {
        int n = t - 32; float a = stb[n];
        for (int k = 0; k < 128; k++) a = fmaf(hsh[k], stw[n * 128 + k], a);
        o_style[b * 8 + n] = a;
    } else if (t < 56) {
        int n = t - 40; float a = cb2[n];
        for (int k = 0; k < 128; k++) a = fmaf(hsh[k], cw_[n * 128 + k], a);
        o_cap[b * 16 + n] = a;
    } else if (t < 80) {
        int n = t - 56; float a = ob2[n];
        for (int k = 0; k < 128; k++) a = fmaf(hsh[k], ow_[n * 128 + k], a);
        o_op[b * 24 + n] = a;
    }
    {
        float a = dib[t];
        for (int k = 0; k < 128; k++) a = fmaf(hsh[k], diw[t * 128 + k], a);
        h0[b * 160 + t] = tanhf(a);
    }
}

// ---------------- generic bf16 MFMA GEMM: C[M,N] = A[M,K]@W[N,K]^T (+bias, epi, res) ----------------
// A bf16 [M][lda]; W f32 [N][K] (rounded to bf16 during staging). BM=BN=64, 4 waves (2x2).
// epi: 0=none 2=tanh 3=softplus->decay(alog[n])
template<int K>
__launch_bounds__(256)
__global__ void mm_bf16(const short* __restrict__ A, int lda,
                        const float* __restrict__ W,
                        const float* __restrict__ bias, int N,
                        int epi, const float* __restrict__ alog,
                        const float* __restrict__ res, int ldres,
                        float* __restrict__ outF, short* __restrict__ outB, int ldc) {
    constexpr int CH = K / 8, KP = K + 8;
    __shared__ __align__(16) short As[64][KP];
    __shared__ __align__(16) short Ws[64][KP];
    const int m0 = blockIdx.x * 64, n0 = blockIdx.y * 64;
    const int tid = threadIdx.x;

    #pragma unroll
    for (int it = 0; it < CH / 4; ++it) {
        int idx = tid + it * 256;
        int r = idx / CH, c = idx % CH;
        *(bf16x8*)&As[r][c * 8] = *(const bf16x8*)&A[(long)(m0 + r) * lda + c * 8];
    }
    #pragma unroll
    for (int it = 0; it < CH / 4; ++it) {
        int idx = tid + it * 256;
        int r = idx / CH, c = idx % CH;
        int gn = n0 + r;
        short tmp[8];
        if (gn < N) {
            const float* wp = &W[(long)gn * K + c * 8];
            #pragma unroll
            for (int q = 0; q < 8; q++) tmp[q] = f2bf(wp[q]);
        } else {
            #pragma unroll
            for (int q = 0; q < 8; q++) tmp[q] = 0;
        }
        *(bf16x8*)&Ws[r][c * 8] = *(bf16x8*)tmp;
    }
    __syncthreads();

    const int wave = tid >> 6, lane = tid & 63;
    const int wm = wave >> 1, wn = wave & 1;
    const int fr = lane & 15, kg = lane >> 4;

    f32x4 acc[2][2];
    #pragma unroll
    for (int i = 0; i < 2; i++)
        #pragma unroll
        for (int j = 0; j < 2; j++) acc[i][j] = (f32x4){0.f, 0.f, 0.f, 0.f};

    #pragma unroll
    for (int ks = 0; ks < K / 32; ++ks) {
        int kb = ks * 32 + kg * 8;
        bf16x8 a0 = *(const bf16x8*)&As[wm * 32 + fr][kb];
        bf16x8 a1 = *(const bf16x8*)&As[wm * 32 + 16 + fr][kb];
        bf16x8 w0 = *(const bf16x8*)&Ws[wn * 32 + fr][kb];
        bf16x8 w1 = *(const bf16x8*)&Ws[wn * 32 + 16 + fr][kb];
        acc[0][0] = __builtin_amdgcn_mfma_f32_16x16x32_bf16(a0, w0, acc[0][0], 0, 0, 0);
        acc[0][1] = __builtin_amdgcn_mfma_f32_16x16x32_bf16(a0, w1, acc[0][1], 0, 0, 0);
        acc[1][0] = __builtin_amdgcn_mfma_f32_16x16x32_bf16(a1, w0, acc[1][0], 0, 0, 0);
        acc[1][1] = __builtin_amdgcn_mfma_f32_16x16x32_bf16(a1, w1, acc[1][1], 0, 0, 0);
    }

    // C/D layout (HW-verified): col = lane&15 (+subtile), row = (lane>>4)*4 + reg
    #pragma unroll
    for (int i = 0; i < 2; i++) {
        #pragma unroll
        for (int j = 0; j < 2; j++) {
            int col = n0 + wn * 32 + j * 16 + fr;
            if (col >= N) continue;
            float bv = bias ? bias[col] : 0.f;
            float al = (epi == 3) ? -expf(alog[col]) : 0.f;
            #pragma unroll
            for (int q = 0; q < 4; q++) {
                int row = m0 + wm * 32 + i * 16 + kg * 4 + q;
                float v = acc[i][j][q] + bv;
                if (epi == 2) v = tanhf(v);
                else if (epi == 3) { float dt = softplus_f(v) + 1e-4f; v = expf(al * dt); }
                if (res) v += res[(long)row * ldres + col];
                if (outF) outF[(long)row * ldc + col] = v;
                else      outB[(long)row * ldc + col] = f2bf(v);
            }
        }
    }
}

// ---------------- GRU decoder: w_hh in registers, 4-way ILP dot, bf16 output ----------------
__launch_bounds__(512, 1)
__global__ void gru_kernel(const float* __restrict__ gx, const float* __restrict__ h0,
                           const float* __restrict__ whh, const float* __restrict__ bhh,
                           short* __restrict__ dec_out) {
    int b = blockIdx.x, tid = threadIdx.x;   // 512 threads
    __shared__ float hs[160];
    __shared__ float gh[480];
    f32x4 w[40];
    float bh = 0.f;
    if (tid < 480) {
        bh = bhh[tid];
        const f32x4* wrow = reinterpret_cast<const f32x4*>(whh + tid * 160);
        #pragma unroll
        for (int q = 0; q < 40; q++) w[q] = wrow[q];
    }
    if (tid < 160) hs[tid] = h0[b * 160 + tid];
    __syncthreads();
    for (int t = 0; t < TDEC; ++t) {
        if (tid < 480) {
            const f32x4* hv = reinterpret_cast<const f32x4*>(hs);
            float a0 = bh, a1 = 0.f, a2 = 0.f, a3 = 0.f;
            #pragma unroll
            for (int q = 0; q < 40; q += 4) {
                f32x4 ha = hv[q],     wa = w[q];
                f32x4 hb = hv[q + 1], wb = w[q + 1];
                f32x4 hc = hv[q + 2], wc = w[q + 2];
                f32x4 hd = hv[q + 3], wd = w[q + 3];
                a0 = fmaf(ha.w, wa.w, fmaf(ha.z, wa.z, fmaf(ha.y, wa.y, fmaf(ha.x, wa.x, a0))));
                a1 = fmaf(hb.w, wb.w, fmaf(hb.z, wb.z, fmaf(hb.y, wb.y, fmaf(hb.x, wb.x, a1))));
                a2 = fmaf(hc.w, wc.w, fmaf(hc.z, wc.z, fmaf(hc.y, wc.y, fmaf(hc.x, wc.x, a2))));
                a3 = fmaf(hd.w, wd.w, fmaf(hd.z, wd.z, fmaf(hd.y, wd.y, fmaf(hd.x, wd.x, a3))));
            }
            gh[tid] = (a0 + a1) + (a2 + a3);
        }
        __syncthreads();
        if (tid < 160) {
            const float* gxt = gx + ((long)b * TDEC + t) * 480;
            float r = sigmoid_f(gxt[tid] + gh[tid]);
            float z = sigmoid_f(gxt[160 + tid] + gh[160 + tid]);
            float n = tanhf(gxt[320 + tid] + r * gh[320 + tid]);
            float hnew = (1.f - z) * n + z * hs[tid];
            dec_out[((long)b * TDEC + t) * 160 + tid] = f2bf(hnew);
            hs[tid] = hnew;
        }
        __syncthreads();
    }
}

// ---------------- f32 -> bf16 bits cast ----------------
__global__ void castbf_kernel(const float* __restrict__ in, short* __restrict__ out, int n) {
    int i = blockIdx.x * blockDim.x + threadIdx.x;
    int stride = gridDim.x * blockDim.x;
    for (; i < n; i += stride) out[i] = f2bf(in[i]);
}

// ---------------- vocab projection: bf16 MFMA, coalesced f32x4 epilogue via LDS ----------------
// BM=128, BN=64. grid = (N/64, M/128). 256 threads = 4 waves (2x2).
__launch_bounds__(256)
__global__ void vocab_gemm(const short* __restrict__ A,   // [4096][160] bf16
                           const short* __restrict__ W,   // [32000][160] bf16
                           const float* __restrict__ bias,
                           float* __restrict__ C) {
    __shared__ __align__(16) short As[128][168];   // 43 KB; reused as f32 C-tile (32 KB)
    __shared__ __align__(16) short Ws[64][168];
    int n0 = blockIdx.x * 64, m0 = blockIdx.y * 128;
    int tid = threadIdx.x;

    #pragma unroll
    for (int it = 0; it < 10; ++it) {
        int idx = tid + it * 256;
        int r = idx / 20, c8 = idx % 20;
        *(bf16x8*)&As[r][c8 * 8] = *(const bf16x8*)&A[(long)(m0 + r) * 160 + c8 * 8];
    }
    #pragma unroll
    for (int it = 0; it < 5; ++it) {
        int idx = tid + it * 256;
        int r = idx / 20, c8 = idx % 20;
        *(bf16x8*)&Ws[r][c8 * 8] = *(const bf16x8*)&W[(long)(n0 + r) * 160 + c8 * 8];
    }
    __syncthreads();

    int wave = tid >> 6, lane = tid & 63;
    int wm = wave >> 1, wn = wave & 1;
    int fr = lane & 15, kg = lane >> 4;

    f32x4 acc[4][2];
    #pragma unroll
    for (int i = 0; i < 4; i++)
        #pragma unroll
        for (int j = 0; j < 2; j++) acc[i][j] = (f32x4){0.f, 0.f, 0.f, 0.f};

    #pragma unroll
    for (int ks = 0; ks < 5; ++ks) {
        int kb = ks * 32 + kg * 8;
        bf16x8 a[4], bfr[2];
        #pragma unroll
        for (int i = 0; i < 4; i++)
            a[i] = *(const bf16x8*)&As[wm * 64 + i * 16 + fr][kb];
        #pragma unroll
        for (int j = 0; j < 2; j++)
            bfr[j] = *(const bf16x8*)&Ws[wn * 32 + j * 16 + fr][kb];
        #pragma unroll
        for (int i = 0; i < 4; i++)
            #pragma unroll
            for (int j = 0; j < 2; j++)
                acc[i][j] = __builtin_amdgcn_mfma_f32_16x16x32_bf16(a[i], bfr[j], acc[i][j], 0, 0, 0);
    }

    // stage C tile in LDS (reuse As), then fully-coalesced f32x4 stores
    __syncthreads();
    float* Cs = (float*)&As[0][0];   // [128][64]
    #pragma unroll
    for (int i = 0; i < 4; i++) {
        #pragma unroll
        for (int j = 0; j < 2; j++) {
            int col = wn * 32 + j * 16 + fr;
            #pragma unroll
            for (int q = 0; q < 4; q++) {
                int row = wm * 64 + i * 16 + kg * 4 + q;
                Cs[row * 64 + col] = acc[i][j][q];
            }
        }
    }
    __syncthreads();
    #pragma unroll
    for (int it = 0; it < 8; ++it) {
        int idx = tid + it * 256;        // 2048 f32x4 chunks
        int row = idx >> 4, c4 = (idx & 15) * 4;
        f32x4 v = *(f32x4*)&Cs[row * 64 + c4];
        int gc = n0 + c4;
        v.x += bias[gc]; v.y += bias[gc + 1]; v.z += bias[gc + 2]; v.w += bias[gc + 3];
        *(f32x4*)&C[(long)(m0 + row) * VOCAB + gc] = v;
    }
}

extern "C" void kernel_launch(void* const* d_in, const int* in_sizes, int n_in,
                              void* d_out, int out_size, void* d_ws, size_t ws_size,
                              hipStream_t stream) {
    const int* x        = (const int*)d_in[0];
    const int* lengths  = (const int*)d_in[1];
    const int* resp_in  = (const int*)d_in[2];
    const float* emb_table = (const float*)d_in[3];
    const float* m_norm_g  = (const float*)d_in[4];
    const float* m_norm_b  = (const float*)d_in[5];
    const float* m_in_w    = (const float*)d_in[6];
    const float* m_in_b    = (const float*)d_in[7];
    const float* m_conv_w  = (const float*)d_in[8];
    const float* m_conv_b  = (const float*)d_in[9];
    const float* m_dt_w    = (const float*)d_in[10];
    const float* m_dt_b    = (const float*)d_in[11];
    const float* m_b_w     = (const float*)d_in[12];
    const float* m_b_b     = (const float*)d_in[13];
    const float* m_c_w     = (const float*)d_in[14];
    const float* m_c_b     = (const float*)d_in[15];
    const float* m_a_log   = (const float*)d_in[16];
    const float* m_d       = (const float*)d_in[17];
    const float* m_out_w   = (const float*)d_in[18];
    const float* m_out_b   = (const float*)d_in[19];
    const float* pool_g    = (const float*)d_in[20];
    const float* pool_b    = (const float*)d_in[21];
    const float* shared_w  = (const float*)d_in[22];
    const float* shared_b  = (const float*)d_in[23];
    const float* intent_w  = (const float*)d_in[24];
    const float* intent_b  = (const float*)d_in[25];
    const float* style_w   = (const float*)d_in[26];
    const float* style_b   = (const float*)d_in[27];
    const float* cap_w     = (const float*)d_in[28];
    const float* cap_b     = (const float*)d_in[29];
    const float* op_w      = (const float*)d_in[30];
    const float* op_b      = (const float*)d_in[31];
    const float* dec_emb   = (const float*)d_in[32];
    const float* dec_init_w = (const float*)d_in[33];
    const float* dec_init_b = (const float*)d_in[34];
    const float* gru_w_ih  = (const float*)d_in[35];
    const float* gru_w_hh  = (const float*)d_in[36];
    const float* gru_b_ih  = (const float*)d_in[37];
    const float* gru_b_hh  = (const float*)d_in[38];
    const float* dec_out_w = (const float*)d_in[39];
    const float* dec_out_b = (const float*)d_in[40];

    float* out = (float*)d_out;
    const long o_intent = 0;
    const long o_style  = 32 * 32;
    const long o_cap    = o_style + 32 * 8;
    const long o_op     = o_cap + 32 * 16;
    const long o_logits = o_op + 32 * 24;
    const long o_h      = o_logits + (long)BDIM * TDEC * VOCAB;

    const int R = BDIM * TDIM;                 // 16384
    const int Rd = BDIM * TDEC;                // 4096

    // large scratch inside d_out logits region (524 MB capacity, ~48 MB used);
    // vocab_gemm is the final dispatch and fully overwrites this region.
    char* Sb = (char*)(out + o_logits);
    short* xnb   = (short*)Sb;  Sb += (long)R * 128 * 2;    // LN output; also dec_in [4096][128]
    short* projb = (short*)Sb;  Sb += (long)R * 256 * 2;    // in-proj output (bf16)
    float* gx    = (float*)Sb;  Sb += (long)Rd * 480 * 4;   // GRU input gates
    float* sdat  = (float*)Sb;  Sb += (long)R * 192 * 4;    // decay|bt|ct (f32)
    float* hseq  = (float*)Sb;  Sb += (long)R * 128 * 4;    // residual stream (f32)
    short* mixb  = (short*)Sb;  Sb += (long)R * 192 * 2;    // conv||scan output (bf16)

    // d_ws (~11.6 MB, proven to fit in round 7)
    int* flags   = (int*)d_ws;
    float* wsf   = (float*)d_ws + 16;
    float* h0    = wsf;           wsf += 32 * 160;
    short* dec_obf = (short*)wsf;                           // [4096][160] bf16
    short* w_bf  = dec_obf + (long)Rd * HID;                // [32000][160] bf16

    detect_kernel<<<1, 64, 0, stream>>>(x, lengths, resp_in, flags);
    castbf_kernel<<<2048, 256, 0, stream>>>(dec_out_w, w_bf, VOCAB * HID);

    // ---- encoder ----
    embed_kernel<<<4096, 256, 0, stream>>>(x, emb_table, hseq, R * 128, flags, 0);

    for (int i = 0; i < 2; ++i) {
        ln_kernel<<<R, 128, 0, stream>>>(hseq, m_norm_g + i * 128, m_norm_b + i * 128, xnb);
        // in-proj: [16384,256] = xnb[16384,128] @ in_w^T  -> bf16 projb
        mm_bf16<128><<<dim3(R / 64, 4), 256, 0, stream>>>(
            xnb, 128, m_in_w + i * 256 * 128, m_in_b + i * 256, 256,
            0, nullptr, nullptr, 0, nullptr, projb, 256);
        conv_kernel<<<8192, 256, 0, stream>>>(projb, m_conv_w + i * 384, m_conv_b + i * 128,
                                              m_d + i * 128, mixb, R * 128);
        // z-projections (A = z-half of projb): decay / bt / ct -> f32 sdat (strided)
        mm_bf16<128><<<dim3(R / 64, 1), 256, 0, stream>>>(
            projb + 128, 256, m_dt_w + i * 8192, m_dt_b + i * 64, 64,
            3, m_a_log + i * 64, nullptr, 0, sdat, nullptr, 192);
        mm_bf16<128><<<dim3(R / 64, 1), 256, 0, stream>>>(
            projb + 128, 256, m_b_w + i * 8192, m_b_b + i * 64, 64,
            2, nullptr, nullptr, 0, sdat + 64, nullptr, 192);
        mm_bf16<128><<<dim3(R / 64, 1), 256, 0, stream>>>(
            projb + 128, 256, m_c_w + i * 8192, m_c_b + i * 64, 64,
            2, nullptr, nullptr, 0, sdat + 128, nullptr, 192);
        scan2_kernel<<<BDIM, 512, 0, stream>>>(sdat, mixb);
        // out-proj + residual (res==out in-place: each element touched by one lane)
        mm_bf16<192><<<dim3(R / 64, 2), 256, 0, stream>>>(
            mixb, 192, m_out_w + i * 128 * 192, m_out_b + i * 128, 128,
            0, nullptr, hseq, 128, hseq, nullptr, 128);
    }

    // ---- fused pooled heads + dec_init ----
    heads_kernel<<<BDIM, 160, 0, stream>>>(hseq, lengths, flags,
        pool_g, pool_b, shared_w, shared_b,
        intent_w, intent_b, style_w, style_b, cap_w, cap_b, op_w, op_b,
        dec_init_w, dec_init_b,
        out + o_intent, out + o_style, out + o_cap, out + o_op, out + o_h, h0);

    // ---- decoder ----
    embed_bf_kernel<<<2048, 256, 0, stream>>>(resp_in, dec_emb, xnb, Rd * 128, flags, 2);
    mm_bf16<128><<<dim3(Rd / 64, 8), 256, 0, stream>>>(
        xnb, 128, gru_w_ih, gru_b_ih, 480,
        0, nullptr, nullptr, 0, gx, nullptr, 480);
    gru_kernel<<<BDIM, 512, 0, stream>>>(gx, h0, gru_w_hh, gru_b_hh, dec_obf);

    // ---- vocab projection: final dispatch, overwrites the d_out scratch region ----
    vocab_gemm<<<dim3(VOCAB / 64, Rd / 128), 256, 0, stream>>>(
        dec_obf, w_bf, dec_out_b, out + o_logits);
}

// Round 9
// 633.676 us; speedup vs baseline: 6.4972x; 1.0134x over previous
//
#include <hip/hip_runtime.h>
#include <hip/hip_bf16.h>

#define EMBED 128
#define STATE 64
#define HID   160
#define VOCAB 32000
#define BDIM  32
#define TDIM  512
#define TDEC  128

typedef __attribute__((ext_vector_type(4))) float f32x4;
typedef __attribute__((ext_vector_type(8))) short bf16x8;

__device__ inline float softplus_f(float x) { return x > 20.f ? x : log1pf(expf(x)); }
__device__ inline float sigmoid_f(float x) { return 1.f / (1.f + expf(-x)); }
__device__ inline short f2bf(float x) {
    __hip_bfloat16 v = __float2bfloat16(x);
    return *reinterpret_cast<short*>(&v);
}
__device__ inline float bf2f(short u) {
    union { unsigned int i; float f; } cv;
    cv.i = ((unsigned int)(unsigned short)u) << 16;
    return cv.f;
}

// ---------------- prep: vocab-weight f32->bf16 cast + int64-staging detect ----------------
__global__ void prep_kernel(const float* __restrict__ w, short* __restrict__ wb, int n,
                            const int* __restrict__ x, const int* __restrict__ lengths,
                            const int* __restrict__ resp, int* __restrict__ flags) {
    if (blockIdx.x == 0 && threadIdx.x == 0) {
        int f = 1;
        for (int i = 0; i < 32; i++) if (x[2 * i + 1] != 0) { f = 0; break; }
        flags[0] = f;
        f = 1;
        for (int i = 0; i < 16; i++) if (lengths[2 * i + 1] != 0) { f = 0; break; }
        flags[1] = f;
        f = 1;
        for (int i = 0; i < 32; i++) if (resp[2 * i + 1] != 0) { f = 0; break; }
        flags[2] = f;
    }
    int i = blockIdx.x * blockDim.x + threadIdx.x;
    int stride = gridDim.x * blockDim.x;
    for (; i < n; i += stride) wb[i] = f2bf(w[i]);
}

// ---------------- embedding lookup: f32 out (encoder residual stream) ----------------
__global__ void embed_kernel(const int* __restrict__ tok, const float* __restrict__ table,
                             float* __restrict__ out, int total,
                             const int* __restrict__ flags, int fidx) {
    int mode = flags[fidx];
    int i = blockIdx.x * blockDim.x + threadIdx.x;
    int stride = gridDim.x * blockDim.x;
    for (; i < total; i += stride) {
        int r = i >> 7, e = i & 127;
        int t = mode ? tok[2 * r] : tok[r];
        out[i] = table[(long)t * EMBED + e];
    }
}

// ---------------- in-projection with fused LayerNorm: projb[16384][256] (bf16) ----------------
// grid (R/64, 4), 256 threads = 4 waves (2x2). A = LN(hseq row) staged to bf16.
__launch_bounds__(256)
__global__ void mm_inproj(const float* __restrict__ hseq,
                          const float* __restrict__ g, const float* __restrict__ bta,
                          const float* __restrict__ W, const float* __restrict__ bias,
                          short* __restrict__ projb) {
    __shared__ __align__(16) short As[64][136];
    __shared__ __align__(16) short Ws[64][136];
    __shared__ float rsum[64][4], rsum2[64][4];
    const int m0 = blockIdx.x * 64, n0 = blockIdx.y * 64;
    const int tid = threadIdx.x;

    // --- A staging: LN(128) per row; 4 threads/row, 32 elems each ---
    {
        int row = tid >> 2, part = tid & 3;
        const float* src = &hseq[(long)(m0 + row) * 128 + part * 32];
        f32x4 v[8];
        float s = 0.f, s2 = 0.f;
        #pragma unroll
        for (int q = 0; q < 8; q++) {
            v[q] = *(const f32x4*)&src[q * 4];
            s  += v[q].x + v[q].y + v[q].z + v[q].w;
            s2 += v[q].x * v[q].x + v[q].y * v[q].y + v[q].z * v[q].z + v[q].w * v[q].w;
        }
        rsum[row][part] = s; rsum2[row][part] = s2;
        __syncthreads();
        float tot  = rsum[row][0] + rsum[row][1] + rsum[row][2] + rsum[row][3];
        float tot2 = rsum2[row][0] + rsum2[row][1] + rsum2[row][2] + rsum2[row][3];
        float mu = tot * (1.f / 128.f);
        float var = tot2 * (1.f / 128.f) - mu * mu;
        float rstd = rsqrtf(var + 1e-5f);
        #pragma unroll
        for (int q = 0; q < 8; q++) {
            int c = part * 32 + q * 4;
            short4 t4;
            t4.x = f2bf((v[q].x - mu) * rstd * g[c + 0] + bta[c + 0]);
            t4.y = f2bf((v[q].y - mu) * rstd * g[c + 1] + bta[c + 1]);
            t4.z = f2bf((v[q].z - mu) * rstd * g[c + 2] + bta[c + 2]);
            t4.w = f2bf((v[q].w - mu) * rstd * g[c + 3] + bta[c + 3]);
            *(short4*)&As[row][c] = t4;
        }
    }
    // --- W staging: f32 -> bf16 ---
    #pragma unroll
    for (int it = 0; it < 4; ++it) {
        int idx = tid + it * 256;
        int rr = idx >> 4, cc = idx & 15;
        const float* wp = &W[(long)(n0 + rr) * 128 + cc * 8];
        short t8[8];
        #pragma unroll
        for (int q = 0; q < 8; q++) t8[q] = f2bf(wp[q]);
        *(bf16x8*)&Ws[rr][cc * 8] = *(bf16x8*)t8;
    }
    __syncthreads();

    const int wave = tid >> 6, lane = tid & 63;
    const int wm = wave >> 1, wn = wave & 1;
    const int fr = lane & 15, kg = lane >> 4;
    f32x4 acc[2][2];
    #pragma unroll
    for (int i = 0; i < 2; i++)
        #pragma unroll
        for (int j = 0; j < 2; j++) acc[i][j] = (f32x4){0.f, 0.f, 0.f, 0.f};
    #pragma unroll
    for (int ks = 0; ks < 4; ++ks) {
        int kb = ks * 32 + kg * 8;
        bf16x8 a0 = *(const bf16x8*)&As[wm * 32 + fr][kb];
        bf16x8 a1 = *(const bf16x8*)&As[wm * 32 + 16 + fr][kb];
        bf16x8 w0 = *(const bf16x8*)&Ws[wn * 32 + fr][kb];
        bf16x8 w1 = *(const bf16x8*)&Ws[wn * 32 + 16 + fr][kb];
        acc[0][0] = __builtin_amdgcn_mfma_f32_16x16x32_bf16(a0, w0, acc[0][0], 0, 0, 0);
        acc[0][1] = __builtin_amdgcn_mfma_f32_16x16x32_bf16(a0, w1, acc[0][1], 0, 0, 0);
        acc[1][0] = __builtin_amdgcn_mfma_f32_16x16x32_bf16(a1, w0, acc[1][0], 0, 0, 0);
        acc[1][1] = __builtin_amdgcn_mfma_f32_16x16x32_bf16(a1, w1, acc[1][1], 0, 0, 0);
    }
    #pragma unroll
    for (int i = 0; i < 2; i++)
        #pragma unroll
        for (int j = 0; j < 2; j++) {
            int col = n0 + wn * 32 + j * 16 + fr;
            float bv = bias[col];
            #pragma unroll
            for (int q = 0; q < 4; q++) {
                int row = m0 + wm * 32 + i * 16 + kg * 4 + q;
                projb[(long)row * 256 + col] = f2bf(acc[i][j][q] + bv);
            }
        }
}

// ---------------- z-projections: one dispatch, grid (R/64, 3); sel: 0=decay 1=bt 2=ct ----------------
__launch_bounds__(256)
__global__ void mm_z(const short* __restrict__ projb,
                     const float* __restrict__ dtw, const float* __restrict__ dtb,
                     const float* __restrict__ alog,
                     const float* __restrict__ bw, const float* __restrict__ bb_,
                     const float* __restrict__ cw, const float* __restrict__ cb_,
                     float* __restrict__ sdat) {
    __shared__ __align__(16) short As[64][136];
    __shared__ __align__(16) short Ws[64][136];
    const int m0 = blockIdx.x * 64, sel = blockIdx.y;
    const int tid = threadIdx.x;
    const float* W = sel == 0 ? dtw : (sel == 1 ? bw : cw);
    const float* B = sel == 0 ? dtb : (sel == 1 ? bb_ : cb_);

    #pragma unroll
    for (int it = 0; it < 4; ++it) {
        int idx = tid + it * 256;
        int rr = idx >> 4, cc = idx & 15;
        *(bf16x8*)&As[rr][cc * 8] = *(const bf16x8*)&projb[(long)(m0 + rr) * 256 + 128 + cc * 8];
    }
    #pragma unroll
    for (int it = 0; it < 4; ++it) {
        int idx = tid + it * 256;
        int rr = idx >> 4, cc = idx & 15;
        const float* wp = &W[(long)rr * 128 + cc * 8];
        short t8[8];
        #pragma unroll
        for (int q = 0; q < 8; q++) t8[q] = f2bf(wp[q]);
        *(bf16x8*)&Ws[rr][cc * 8] = *(bf16x8*)t8;
    }
    __syncthreads();

    const int wave = tid >> 6, lane = tid & 63;
    const int wm = wave >> 1, wn = wave & 1;
    const int fr = lane & 15, kg = lane >> 4;
    f32x4 acc[2][2];
    #pragma unroll
    for (int i = 0; i < 2; i++)
        #pragma unroll
        for (int j = 0; j < 2; j++) acc[i][j] = (f32x4){0.f, 0.f, 0.f, 0.f};
    #pragma unroll
    for (int ks = 0; ks < 4; ++ks) {
        int kb = ks * 32 + kg * 8;
        bf16x8 a0 = *(const bf16x8*)&As[wm * 32 + fr][kb];
        bf16x8 a1 = *(const bf16x8*)&As[wm * 32 + 16 + fr][kb];
        bf16x8 w0 = *(const bf16x8*)&Ws[wn * 32 + fr][kb];
        bf16x8 w1 = *(const bf16x8*)&Ws[wn * 32 + 16 + fr][kb];
        acc[0][0] = __builtin_amdgcn_mfma_f32_16x16x32_bf16(a0, w0, acc[0][0], 0, 0, 0);
        acc[0][1] = __builtin_amdgcn_mfma_f32_16x16x32_bf16(a0, w1, acc[0][1], 0, 0, 0);
        acc[1][0] = __builtin_amdgcn_mfma_f32_16x16x32_bf16(a1, w0, acc[1][0], 0, 0, 0);
        acc[1][1] = __builtin_amdgcn_mfma_f32_16x16x32_bf16(a1, w1, acc[1][1], 0, 0, 0);
    }
    #pragma unroll
    for (int i = 0; i < 2; i++)
        #pragma unroll
        for (int j = 0; j < 2; j++) {
            int n = wn * 32 + j * 16 + fr;
            float bv = B[n];
            float al = (sel == 0) ? -expf(alog[n]) : 0.f;
            #pragma unroll
            for (int q = 0; q < 4; q++) {
                int row = m0 + wm * 32 + i * 16 + kg * 4 + q;
                float v = acc[i][j][q] + bv;
                if (sel == 0) { float dt = softplus_f(v) + 1e-4f; v = expf(al * dt); }
                else v = tanhf(v);
                sdat[(long)row * 192 + sel * 64 + n] = v;
            }
        }
}

// ---------------- fused conv + chunked SSM scan; one block (512 thr) per batch ----------------
__global__ void convscan_kernel(const short* __restrict__ projb,
                                const float* __restrict__ cw, const float* __restrict__ cb,
                                const float* __restrict__ dvec,
                                const float* __restrict__ sdat, short* __restrict__ mixb) {
    int b = blockIdx.x, tid = threadIdx.x;   // 512 threads
    long rbase = (long)b * TDIM;
    // conv phase (writes mixb[:, :128]; disjoint from scan output -> no barrier)
    for (int idx = tid; idx < TDIM * 128; idx += 512) {
        int t = idx >> 7, e = idx & 127;
        long r = rbase + t;
        float x0 = bf2f(projb[r * 256 + e]);
        float xm = (t > 0)        ? bf2f(projb[(r - 1) * 256 + e]) : 0.f;
        float xp = (t < TDIM - 1) ? bf2f(projb[(r + 1) * 256 + e]) : 0.f;
        float v = cw[e * 3 + 0] * xm + cw[e * 3 + 1] * x0 + cw[e * 3 + 2] * xp + cb[e];
        mixb[r * 192 + e] = f2bf(tanhf(v) * dvec[e]);
    }
    // scan phase: 8 chunks x 64 states
    int c = tid >> 6, s = tid & 63;
    __shared__ float SA[8][64], SB[8][64], SI[8][64];
    int t0 = c * 64;
    float Aacc = 1.f, Bacc = 0.f;
    #pragma unroll 4
    for (int t = t0; t < t0 + 64; ++t) {
        const float* row = sdat + (rbase + t) * 192;
        float d = row[s], bt = row[64 + s];
        Bacc = Bacc * d + bt;
        Aacc *= d;
    }
    SA[c][s] = Aacc; SB[c][s] = Bacc;
    __syncthreads();
    if (c == 0) {
        float st = 0.f;
        #pragma unroll
        for (int cc = 0; cc < 8; ++cc) {
            SI[cc][s] = st;
            st = SB[cc][s] + SA[cc][s] * st;
        }
    }
    __syncthreads();
    float st = SI[c][s];
    #pragma unroll 4
    for (int t = t0; t < t0 + 64; ++t) {
        const float* row = sdat + (rbase + t) * 192;
        st = st * row[s] + row[64 + s];
        mixb[(rbase + t) * 192 + 128 + s] = f2bf(row[128 + s] * st);
    }
}

// ---------------- out-projection + residual (in-place on hseq): K=192 ----------------
__launch_bounds__(256)
__global__ void mm_out(const short* __restrict__ mixb,
                       const float* __restrict__ W, const float* __restrict__ bias,
                       float* __restrict__ hseq) {
    __shared__ __align__(16) short As[64][200];
    __shared__ __align__(16) short Ws[64][200];
    const int m0 = blockIdx.x * 64, n0 = blockIdx.y * 64;
    const int tid = threadIdx.x;

    #pragma unroll
    for (int it = 0; it < 6; ++it) {
        int idx = tid + it * 256;
        int rr = idx / 24, cc = idx % 24;
        *(bf16x8*)&As[rr][cc * 8] = *(const bf16x8*)&mixb[(long)(m0 + rr) * 192 + cc * 8];
    }
    #pragma unroll
    for (int it = 0; it < 6; ++it) {
        int idx = tid + it * 256;
        int rr = idx / 24, cc = idx % 24;
        const float* wp = &W[(long)(n0 + rr) * 192 + cc * 8];
        short t8[8];
        #pragma unroll
        for (int q = 0; q < 8; q++) t8[q] = f2bf(wp[q]);
        *(bf16x8*)&Ws[rr][cc * 8] = *(bf16x8*)t8;
    }
    __syncthreads();

    const int wave = tid >> 6, lane = tid & 63;
    const int wm = wave >> 1, wn = wave & 1;
    const int fr = lane & 15, kg = lane >> 4;
    f32x4 acc[2][2];
    #pragma unroll
    for (int i = 0; i < 2; i++)
        #pragma unroll
        for (int j = 0; j < 2; j++) acc[i][j] = (f32x4){0.f, 0.f, 0.f, 0.f};
    #pragma unroll
    for (int ks = 0; ks < 6; ++ks) {
        int kb = ks * 32 + kg * 8;
        bf16x8 a0 = *(const bf16x8*)&As[wm * 32 + fr][kb];
        bf16x8 a1 = *(const bf16x8*)&As[wm * 32 + 16 + fr][kb];
        bf16x8 w0 = *(const bf16x8*)&Ws[wn * 32 + fr][kb];
        bf16x8 w1 = *(const bf16x8*)&Ws[wn * 32 + 16 + fr][kb];
        acc[0][0] = __builtin_amdgcn_mfma_f32_16x16x32_bf16(a0, w0, acc[0][0], 0, 0, 0);
        acc[0][1] = __builtin_amdgcn_mfma_f32_16x16x32_bf16(a0, w1, acc[0][1], 0, 0, 0);
        acc[1][0] = __builtin_amdgcn_mfma_f32_16x16x32_bf16(a1, w0, acc[1][0], 0, 0, 0);
        acc[1][1] = __builtin_amdgcn_mfma_f32_16x16x32_bf16(a1, w1, acc[1][1], 0, 0, 0);
    }
    #pragma unroll
    for (int i = 0; i < 2; i++)
        #pragma unroll
        for (int j = 0; j < 2; j++) {
            int col = n0 + wn * 32 + j * 16 + fr;
            float bv = bias[col];
            #pragma unroll
            for (int q = 0; q < 4; q++) {
                int row = m0 + wm * 32 + i * 16 + kg * 4 + q;
                // in-place residual: each element read+written by exactly this lane
                hseq[(long)row * 128 + col] += acc[i][j][q] + bv;
            }
        }
}

// ---------------- gx GEMM with fused decoder-embedding gather: gx[4096][480] ----------------
__launch_bounds__(256)
__global__ void mm_gx(const int* __restrict__ resp, const float* __restrict__ table,
                      const int* __restrict__ flags,
                      const float* __restrict__ W, const float* __restrict__ bias,
                      float* __restrict__ gx) {
    __shared__ __align__(16) short As[64][136];
    __shared__ __align__(16) short Ws[64][136];
    const int m0 = blockIdx.x * 64, n0 = blockIdx.y * 64;
    const int tid = threadIdx.x;
    const int mode = flags[2];

    #pragma unroll
    for (int it = 0; it < 4; ++it) {
        int idx = tid + it * 256;
        int rr = idx >> 4, cc = idx & 15;
        int gr = m0 + rr;
        int tk = mode ? resp[2 * gr] : resp[gr];
        const float* sp = &table[(long)tk * 128 + cc * 8];
        short t8[8];
        #pragma unroll
        for (int q = 0; q < 8; q++) t8[q] = f2bf(sp[q]);
        *(bf16x8*)&As[rr][cc * 8] = *(bf16x8*)t8;
    }
    #pragma unroll
    for (int it = 0; it < 4; ++it) {
        int idx = tid + it * 256;
        int rr = idx >> 4, cc = idx & 15;
        int gn = n0 + rr;
        short t8[8];
        if (gn < 480) {
            const float* wp = &W[(long)gn * 128 + cc * 8];
            #pragma unroll
            for (int q = 0; q < 8; q++) t8[q] = f2bf(wp[q]);
        } else {
            #pragma unroll
            for (int q = 0; q < 8; q++) t8[q] = 0;
        }
        *(bf16x8*)&Ws[rr][cc * 8] = *(bf16x8*)t8;
    }
    __syncthreads();

    const int wave = tid >> 6, lane = tid & 63;
    const int wm = wave >> 1, wn = wave & 1;
    const int fr = lane & 15, kg = lane >> 4;
    f32x4 acc[2][2];
    #pragma unroll
    for (int i = 0; i < 2; i++)
        #pragma unroll
        for (int j = 0; j < 2; j++) acc[i][j] = (f32x4){0.f, 0.f, 0.f, 0.f};
    #pragma unroll
    for (int ks = 0; ks < 4; ++ks) {
        int kb = ks * 32 + kg * 8;
        bf16x8 a0 = *(const bf16x8*)&As[wm * 32 + fr][kb];
        bf16x8 a1 = *(const bf16x8*)&As[wm * 32 + 16 + fr][kb];
        bf16x8 w0 = *(const bf16x8*)&Ws[wn * 32 + fr][kb];
        bf16x8 w1 = *(const bf16x8*)&Ws[wn * 32 + 16 + fr][kb];
        acc[0][0] = __builtin_amdgcn_mfma_f32_16x16x32_bf16(a0, w0, acc[0][0], 0, 0, 0);
        acc[0][1] = __builtin_amdgcn_mfma_f32_16x16x32_bf16(a0, w1, acc[0][1], 0, 0, 0);
        acc[1][0] = __builtin_amdgcn_mfma_f32_16x16x32_bf16(a1, w0, acc[1][0], 0, 0, 0);
        acc[1][1] = __builtin_amdgcn_mfma_f32_16x16x32_bf16(a1, w1, acc[1][1], 0, 0, 0);
    }
    #pragma unroll
    for (int i = 0; i < 2; i++)
        #pragma unroll
        for (int j = 0; j < 2; j++) {
            int col = n0 + wn * 32 + j * 16 + fr;
            if (col >= 480) continue;
            float bv = bias[col];
            #pragma unroll
            for (int q = 0; q < 4; q++) {
                int row = m0 + wm * 32 + i * 16 + kg * 4 + q;
                gx[(long)row * 480 + col] = acc[i][j][q] + bv;
            }
        }
}

// ---------------- fused heads + GRU: one block (512 thr) per batch ----------------
__launch_bounds__(512, 1)
__global__ void gru_heads_kernel(const float* __restrict__ hseq, const int* __restrict__ lengths,
                                 const int* __restrict__ flags,
                                 const float* __restrict__ pg, const float* __restrict__ pb,
                                 const float* __restrict__ sw, const float* __restrict__ sb,
                                 const float* __restrict__ iw_, const float* __restrict__ ib_,
                                 const float* __restrict__ stw, const float* __restrict__ stb,
                                 const float* __restrict__ cw_, const float* __restrict__ cb2,
                                 const float* __restrict__ ow_, const float* __restrict__ ob2,
                                 const float* __restrict__ diw, const float* __restrict__ dib,
                                 const float* __restrict__ gx,
                                 const float* __restrict__ whh, const float* __restrict__ bhh,
                                 float* __restrict__ o_intent, float* __restrict__ o_style,
                                 float* __restrict__ o_cap, float* __restrict__ o_op,
                                 float* __restrict__ o_h,
                                 short* __restrict__ dec_out) {
    int b = blockIdx.x, tid = threadIdx.x;   // 512 threads
    __shared__ float red[4][128];
    __shared__ float pooled[128], hsh[128];
    __shared__ float hs[160], gh[480];
    int lm = flags[1];
    int len = lm ? lengths[2 * b] : lengths[b];

    // ---- masked mean pool (4-way split over T) ----
    {
        int e = tid & 127, ch = tid >> 7;
        float s = 0.f;
        for (int t = ch; t < len; t += 4) s += hseq[((long)b * TDIM + t) * 128 + e];
        red[ch][e] = s;
    }
    __syncthreads();
    if (tid < 128) {
        float s = red[0][tid] + red[1][tid] + red[2][tid] + red[3][tid];
        pooled[tid] = s / (float)(len > 1 ? len : 1);
    }
    __syncthreads();
    // ---- LN(128) ----
    if (tid < 128) red[0][tid] = pooled[tid];
    __syncthreads();
    for (int off = 64; off > 0; off >>= 1) { if (tid < off) red[0][tid] += red[0][tid + off]; __syncthreads(); }
    float mu = red[0][0] / 128.f;
    __syncthreads();
    if (tid < 128) { float d = pooled[tid] - mu; red[0][tid] = d * d; }
    __syncthreads();
    for (int off = 64; off > 0; off >>= 1) { if (tid < off) red[0][tid] += red[0][tid + off]; __syncthreads(); }
    float rstd = rsqrtf(red[0][0] / 128.f + 1e-5f);
    __syncthreads();
    if (tid < 128) pooled[tid] = (pooled[tid] - mu) * rstd * pg[tid] + pb[tid];
    __syncthreads();
    // ---- shared relu ----
    if (tid < 128) {
        float a = sb[tid];
        for (int k = 0; k < 128; k++) a = fmaf(pooled[k], sw[tid * 128 + k], a);
        a = fmaxf(a, 0.f);
        hsh[tid] = a;
        o_h[b * 128 + tid] = a;
    }
    __syncthreads();
    // ---- heads + dec_init ----
    if (tid < 32) {
        float a = ib_[tid];
        for (int k = 0; k < 128; k++) a = fmaf(hsh[k], iw_[tid * 128 + k], a);
        o_intent[b * 32 + tid] = a;
    } else if (tid < 40) {
        int n = tid - 32; float a = stb[n];
        for (int k = 0; k < 128; k++) a = fmaf(hsh[k], stw[n * 128 + k], a);
        o_style[b * 8 + n] = a;
    } else if (tid < 56) {
        int n = tid - 40; float a = cb2[n];
        for (int k = 0; k < 128; k++) a = fmaf(hsh[k], cw_[n * 128 + k], a);
        o_cap[b * 16 + n] = a;
    } else if (tid < 80) {
        int n = tid - 56; float a = ob2[n];
        for (int k = 0; k < 128; k++) a = fmaf(hsh[k], ow_[n * 128 + k], a);
        o_op[b * 24 + n] = a;
    }
    if (tid < 160) {
        float a = dib[tid];
        for (int k = 0; k < 128; k++) a = fmaf(hsh[k], diw[tid * 128 + k], a);
        hs[tid] = tanhf(a);
    }
    // ---- GRU: w_hh rows in registers, 4-way ILP dot ----
    f32x4 w[40];
    float bh = 0.f;
    if (tid < 480) {
        bh = bhh[tid];
        const f32x4* wrow = reinterpret_cast<const f32x4*>(whh + tid * 160);
        #pragma unroll
        for (int q = 0; q < 40; q++) w[q] = wrow[q];
    }
    __syncthreads();
    for (int t = 0; t < TDEC; ++t) {
        if (tid < 480) {
            const f32x4* hv = reinterpret_cast<const f32x4*>(hs);
            float a0 = bh, a1 = 0.f, a2 = 0.f, a3 = 0.f;
            #pragma unroll
            for (int q = 0; q < 40; q += 4) {
                f32x4 ha = hv[q],     wa = w[q];
                f32x4 hb = hv[q + 1], wb = w[q + 1];
                f32x4 hc = hv[q + 2], wc = w[q + 2];
                f32x4 hd = hv[q + 3], wd = w[q + 3];
                a0 = fmaf(ha.w, wa.w, fmaf(ha.z, wa.z, fmaf(ha.y, wa.y, fmaf(ha.x, wa.x, a0))));
                a1 = fmaf(hb.w, wb.w, fmaf(hb.z, wb.z, fmaf(hb.y, wb.y, fmaf(hb.x, wb.x, a1))));
                a2 = fmaf(hc.w, wc.w, fmaf(hc.z, wc.z, fmaf(hc.y, wc.y, fmaf(hc.x, wc.x, a2))));
                a3 = fmaf(hd.w, wd.w, fmaf(hd.z, wd.z, fmaf(hd.y, wd.y, fmaf(hd.x, wd.x, a3))));
            }
            gh[tid] = (a0 + a1) + (a2 + a3);
        }
        __syncthreads();
        if (tid < 160) {
            const float* gxt = gx + ((long)b * TDEC + t) * 480;
            float r = sigmoid_f(gxt[tid] + gh[tid]);
            float z = sigmoid_f(gxt[160 + tid] + gh[160 + tid]);
            float n = tanhf(gxt[320 + tid] + r * gh[320 + tid]);
            float hnew = (1.f - z) * n + z * hs[tid];
            dec_out[((long)b * TDEC + t) * 160 + tid] = f2bf(hnew);
            hs[tid] = hnew;
        }
        __syncthreads();
    }
}

// ---------------- vocab projection: bf16 MFMA, coalesced f32x4 epilogue via LDS ----------------
__launch_bounds__(256)
__global__ void vocab_gemm(const short* __restrict__ A,   // [4096][160] bf16
                           const short* __restrict__ W,   // [32000][160] bf16
                           const float* __restrict__ bias,
                           float* __restrict__ C) {
    __shared__ __align__(16) short As[128][168];   // reused as f32 C-tile
    __shared__ __align__(16) short Ws[64][168];
    int n0 = blockIdx.x * 64, m0 = blockIdx.y * 128;
    int tid = threadIdx.x;

    #pragma unroll
    for (int it = 0; it < 10; ++it) {
        int idx = tid + it * 256;
        int r = idx / 20, c8 = idx % 20;
        *(bf16x8*)&As[r][c8 * 8] = *(const bf16x8*)&A[(long)(m0 + r) * 160 + c8 * 8];
    }
    #pragma unroll
    for (int it = 0; it < 5; ++it) {
        int idx = tid + it * 256;
        int r = idx / 20, c8 = idx % 20;
        *(bf16x8*)&Ws[r][c8 * 8] = *(const bf16x8*)&W[(long)(n0 + r) * 160 + c8 * 8];
    }
    __syncthreads();

    int wave = tid >> 6, lane = tid & 63;
    int wm = wave >> 1, wn = wave & 1;
    int fr = lane & 15, kg = lane >> 4;

    f32x4 acc[4][2];
    #pragma unroll
    for (int i = 0; i < 4; i++)
        #pragma unroll
        for (int j = 0; j < 2; j++) acc[i][j] = (f32x4){0.f, 0.f, 0.f, 0.f};

    #pragma unroll
    for (int ks = 0; ks < 5; ++ks) {
        int kb = ks * 32 + kg * 8;
        bf16x8 a[4], bfr[2];
        #pragma unroll
        for (int i = 0; i < 4; i++)
            a[i] = *(const bf16x8*)&As[wm * 64 + i * 16 + fr][kb];
        #pragma unroll
        for (int j = 0; j < 2; j++)
            bfr[j] = *(const bf16x8*)&Ws[wn * 32 + j * 16 + fr][kb];
        #pragma unroll
        for (int i = 0; i < 4; i++)
            #pragma unroll
            for (int j = 0; j < 2; j++)
                acc[i][j] = __builtin_amdgcn_mfma_f32_16x16x32_bf16(a[i], bfr[j], acc[i][j], 0, 0, 0);
    }

    __syncthreads();
    float* Cs = (float*)&As[0][0];   // [128][64]
    #pragma unroll
    for (int i = 0; i < 4; i++)
        #pragma unroll
        for (int j = 0; j < 2; j++) {
            int col = wn * 32 + j * 16 + fr;
            #pragma unroll
            for (int q = 0; q < 4; q++) {
                int row = wm * 64 + i * 16 + kg * 4 + q;
                Cs[row * 64 + col] = acc[i][j][q];
            }
        }
    __syncthreads();
    #pragma unroll
    for (int it = 0; it < 8; ++it) {
        int idx = tid + it * 256;
        int row = idx >> 4, c4 = (idx & 15) * 4;
        f32x4 v = *(f32x4*)&Cs[row * 64 + c4];
        int gc = n0 + c4;
        v.x += bias[gc]; v.y += bias[gc + 1]; v.z += bias[gc + 2]; v.w += bias[gc + 3];
        *(f32x4*)&C[(long)(m0 + row) * VOCAB + gc] = v;
    }
}

extern "C" void kernel_launch(void* const* d_in, const int* in_sizes, int n_in,
                              void* d_out, int out_size, void* d_ws, size_t ws_size,
                              hipStream_t stream) {
    const int* x        = (const int*)d_in[0];
    const int* lengths  = (const int*)d_in[1];
    const int* resp_in  = (const int*)d_in[2];
    const float* emb_table = (const float*)d_in[3];
    const float* m_norm_g  = (const float*)d_in[4];
    const float* m_norm_b  = (const float*)d_in[5];
    const float* m_in_w    = (const float*)d_in[6];
    const float* m_in_b    = (const float*)d_in[7];
    const float* m_conv_w  = (const float*)d_in[8];
    const float* m_conv_b  = (const float*)d_in[9];
    const float* m_dt_w    = (const float*)d_in[10];
    const float* m_dt_b    = (const float*)d_in[11];
    const float* m_b_w     = (const float*)d_in[12];
    const float* m_b_b     = (const float*)d_in[13];
    const float* m_c_w     = (const float*)d_in[14];
    const float* m_c_b     = (const float*)d_in[15];
    const float* m_a_log   = (const float*)d_in[16];
    const float* m_d       = (const float*)d_in[17];
    const float* m_out_w   = (const float*)d_in[18];
    const float* m_out_b   = (const float*)d_in[19];
    const float* pool_g    = (const float*)d_in[20];
    const float* pool_b    = (const float*)d_in[21];
    const float* shared_w  = (const float*)d_in[22];
    const float* shared_b  = (const float*)d_in[23];
    const float* intent_w  = (const float*)d_in[24];
    const float* intent_b  = (const float*)d_in[25];
    const float* style_w   = (const float*)d_in[26];
    const float* style_b   = (const float*)d_in[27];
    const float* cap_w     = (const float*)d_in[28];
    const float* cap_b     = (const float*)d_in[29];
    const float* op_w      = (const float*)d_in[30];
    const float* op_b      = (const float*)d_in[31];
    const float* dec_emb   = (const float*)d_in[32];
    const float* dec_init_w = (const float*)d_in[33];
    const float* dec_init_b = (const float*)d_in[34];
    const float* gru_w_ih  = (const float*)d_in[35];
    const float* gru_w_hh  = (const float*)d_in[36];
    const float* gru_b_ih  = (const float*)d_in[37];
    const float* gru_b_hh  = (const float*)d_in[38];
    const float* dec_out_w = (const float*)d_in[39];
    const float* dec_out_b = (const float*)d_in[40];

    float* out = (float*)d_out;
    const long o_intent = 0;
    const long o_style  = 32 * 32;
    const long o_cap    = o_style + 32 * 8;
    const long o_op     = o_cap + 32 * 16;
    const long o_logits = o_op + 32 * 24;
    const long o_h      = o_logits + (long)BDIM * TDEC * VOCAB;

    const int R = BDIM * TDIM;                 // 16384
    const int Rd = BDIM * TDEC;                // 4096

    // large scratch inside d_out logits region (524 MB capacity, ~44 MB used);
    // vocab_gemm is the final dispatch and fully overwrites this region.
    char* Sb = (char*)(out + o_logits);
    float* hseq  = (float*)Sb;  Sb += (long)R * 128 * 4;    // residual stream
    short* projb = (short*)Sb;  Sb += (long)R * 256 * 2;    // in-proj output (bf16)
    float* sdat  = (float*)Sb;  Sb += (long)R * 192 * 4;    // decay|bt|ct (f32)
    short* mixb  = (short*)Sb;  Sb += (long)R * 192 * 2;    // conv||scan output (bf16)
    float* gx    = (float*)Sb;  Sb += (long)Rd * 480 * 4;   // GRU input gates

    // d_ws (~11.6 MB, proven to fit)
    int* flags   = (int*)d_ws;
    short* dec_obf = (short*)((float*)d_ws + 16);           // [4096][160] bf16
    short* w_bf  = dec_obf + (long)Rd * HID;                // [32000][160] bf16

    // 1. prep: detect + vocab weight cast
    prep_kernel<<<2048, 256, 0, stream>>>(dec_out_w, w_bf, VOCAB * HID, x, lengths, resp_in, flags);
    // 2. encoder embedding
    embed_kernel<<<4096, 256, 0, stream>>>(x, emb_table, hseq, R * 128, flags, 0);

    for (int i = 0; i < 2; ++i) {
        // 3. LN + in-proj
        mm_inproj<<<dim3(R / 64, 4), 256, 0, stream>>>(
            hseq, m_norm_g + i * 128, m_norm_b + i * 128,
            m_in_w + i * 256 * 128, m_in_b + i * 256, projb);
        // 4. three z-projections in one dispatch
        mm_z<<<dim3(R / 64, 3), 256, 0, stream>>>(
            projb, m_dt_w + i * 8192, m_dt_b + i * 64, m_a_log + i * 64,
            m_b_w + i * 8192, m_b_b + i * 64,
            m_c_w + i * 8192, m_c_b + i * 64, sdat);
        // 5. conv + chunked scan
        convscan_kernel<<<BDIM, 512, 0, stream>>>(
            projb, m_conv_w + i * 384, m_conv_b + i * 128, m_d + i * 128, sdat, mixb);
        // 6. out-proj + residual (in-place)
        mm_out<<<dim3(R / 64, 2), 256, 0, stream>>>(
            mixb, m_out_w + i * 128 * 192, m_out_b + i * 128, hseq);
    }

    // 7. gx GEMM with fused decoder-embedding gather
    mm_gx<<<dim3(Rd / 64, 8), 256, 0, stream>>>(
        resp_in, dec_emb, flags, gru_w_ih, gru_b_ih, gx);
    // 8. fused heads + GRU
    gru_heads_kernel<<<BDIM, 512, 0, stream>>>(
        hseq, lengths, flags,
        pool_g, pool_b, shared_w, shared_b,
        intent_w, intent_b, style_w, style_b, cap_w, cap_b, op_w, op_b,
        dec_init_w, dec_init_b,
        gx, gru_w_hh, gru_b_hh,
        out + o_intent, out + o_style, out + o_cap, out + o_op, out + o_h,
        dec_obf);
    // 9. vocab projection (final dispatch, overwrites d_out scratch region)
    vocab_gemm<<<dim3(VOCAB / 64, Rd / 128), 256, 0, stream>>>(
        dec_obf, w_bf, dec_out_b, out + o_logits);
}

// Round 10
// 507.243 us; speedup vs baseline: 8.1167x; 1.2493x over previous
//
#include <hip/hip_runtime.h>
#include <hip/hip_bf16.h>

#define EMBED 128
#define STATE 64
#define HID   160
#define VOCAB 32000
#define BDIM  32
#define TDIM  512
#define TDEC  128

typedef __attribute__((ext_vector_type(4))) float f32x4;
typedef __attribute__((ext_vector_type(8))) short bf16x8;

__device__ inline float softplus_f(float x) { return x > 20.f ? x : log1pf(expf(x)); }
__device__ inline float sigmoid_f(float x) { return 1.f / (1.f + expf(-x)); }
__device__ inline short f2bf(float x) {
    __hip_bfloat16 v = __float2bfloat16(x);
    return *reinterpret_cast<short*>(&v);
}
__device__ inline float bf2f(short u) {
    union { unsigned int i; float f; } cv;
    cv.i = ((unsigned int)(unsigned short)u) << 16;
    return cv.f;
}

// ---------------- prep: vocab-weight f32->bf16 cast + int64-staging detect ----------------
__global__ void prep_kernel(const float* __restrict__ w, short* __restrict__ wb, int n,
                            const int* __restrict__ x, const int* __restrict__ lengths,
                            const int* __restrict__ resp, int* __restrict__ flags) {
    if (blockIdx.x == 0 && threadIdx.x == 0) {
        int f = 1;
        for (int i = 0; i < 32; i++) if (x[2 * i + 1] != 0) { f = 0; break; }
        flags[0] = f;
        f = 1;
        for (int i = 0; i < 16; i++) if (lengths[2 * i + 1] != 0) { f = 0; break; }
        flags[1] = f;
        f = 1;
        for (int i = 0; i < 32; i++) if (resp[2 * i + 1] != 0) { f = 0; break; }
        flags[2] = f;
    }
    int i = blockIdx.x * blockDim.x + threadIdx.x;
    int stride = gridDim.x * blockDim.x;
    for (; i < n; i += stride) wb[i] = f2bf(w[i]);
}

// ---------------- embedding lookup: f32 out (encoder residual stream) ----------------
__global__ void embed_kernel(const int* __restrict__ tok, const float* __restrict__ table,
                             float* __restrict__ out, int total,
                             const int* __restrict__ flags, int fidx) {
    int mode = flags[fidx];
    int i = blockIdx.x * blockDim.x + threadIdx.x;
    int stride = gridDim.x * blockDim.x;
    for (; i < total; i += stride) {
        int r = i >> 7, e = i & 127;
        int t = mode ? tok[2 * r] : tok[r];
        out[i] = table[(long)t * EMBED + e];
    }
}

// ---------------- in-projection with fused LayerNorm: projb[16384][256] (bf16) ----------------
__launch_bounds__(256)
__global__ void mm_inproj(const float* __restrict__ hseq,
                          const float* __restrict__ g, const float* __restrict__ bta,
                          const float* __restrict__ W, const float* __restrict__ bias,
                          short* __restrict__ projb) {
    __shared__ __align__(16) short As[64][136];
    __shared__ __align__(16) short Ws[64][136];
    __shared__ float rsum[64][4], rsum2[64][4];
    const int m0 = blockIdx.x * 64, n0 = blockIdx.y * 64;
    const int tid = threadIdx.x;

    {
        int row = tid >> 2, part = tid & 3;
        const float* src = &hseq[(long)(m0 + row) * 128 + part * 32];
        f32x4 v[8];
        float s = 0.f, s2 = 0.f;
        #pragma unroll
        for (int q = 0; q < 8; q++) {
            v[q] = *(const f32x4*)&src[q * 4];
            s  += v[q].x + v[q].y + v[q].z + v[q].w;
            s2 += v[q].x * v[q].x + v[q].y * v[q].y + v[q].z * v[q].z + v[q].w * v[q].w;
        }
        rsum[row][part] = s; rsum2[row][part] = s2;
        __syncthreads();
        float tot  = rsum[row][0] + rsum[row][1] + rsum[row][2] + rsum[row][3];
        float tot2 = rsum2[row][0] + rsum2[row][1] + rsum2[row][2] + rsum2[row][3];
        float mu = tot * (1.f / 128.f);
        float var = tot2 * (1.f / 128.f) - mu * mu;
        float rstd = rsqrtf(var + 1e-5f);
        #pragma unroll
        for (int q = 0; q < 8; q++) {
            int c = part * 32 + q * 4;
            short4 t4;
            t4.x = f2bf((v[q].x - mu) * rstd * g[c + 0] + bta[c + 0]);
            t4.y = f2bf((v[q].y - mu) * rstd * g[c + 1] + bta[c + 1]);
            t4.z = f2bf((v[q].z - mu) * rstd * g[c + 2] + bta[c + 2]);
            t4.w = f2bf((v[q].w - mu) * rstd * g[c + 3] + bta[c + 3]);
            *(short4*)&As[row][c] = t4;
        }
    }
    #pragma unroll
    for (int it = 0; it < 4; ++it) {
        int idx = tid + it * 256;
        int rr = idx >> 4, cc = idx & 15;
        const float* wp = &W[(long)(n0 + rr) * 128 + cc * 8];
        short t8[8];
        #pragma unroll
        for (int q = 0; q < 8; q++) t8[q] = f2bf(wp[q]);
        *(bf16x8*)&Ws[rr][cc * 8] = *(bf16x8*)t8;
    }
    __syncthreads();

    const int wave = tid >> 6, lane = tid & 63;
    const int wm = wave >> 1, wn = wave & 1;
    const int fr = lane & 15, kg = lane >> 4;
    f32x4 acc[2][2];
    #pragma unroll
    for (int i = 0; i < 2; i++)
        #pragma unroll
        for (int j = 0; j < 2; j++) acc[i][j] = (f32x4){0.f, 0.f, 0.f, 0.f};
    #pragma unroll
    for (int ks = 0; ks < 4; ++ks) {
        int kb = ks * 32 + kg * 8;
        bf16x8 a0 = *(const bf16x8*)&As[wm * 32 + fr][kb];
        bf16x8 a1 = *(const bf16x8*)&As[wm * 32 + 16 + fr][kb];
        bf16x8 w0 = *(const bf16x8*)&Ws[wn * 32 + fr][kb];
        bf16x8 w1 = *(const bf16x8*)&Ws[wn * 32 + 16 + fr][kb];
        acc[0][0] = __builtin_amdgcn_mfma_f32_16x16x32_bf16(a0, w0, acc[0][0], 0, 0, 0);
        acc[0][1] = __builtin_amdgcn_mfma_f32_16x16x32_bf16(a0, w1, acc[0][1], 0, 0, 0);
        acc[1][0] = __builtin_amdgcn_mfma_f32_16x16x32_bf16(a1, w0, acc[1][0], 0, 0, 0);
        acc[1][1] = __builtin_amdgcn_mfma_f32_16x16x32_bf16(a1, w1, acc[1][1], 0, 0, 0);
    }
    #pragma unroll
    for (int i = 0; i < 2; i++)
        #pragma unroll
        for (int j = 0; j < 2; j++) {
            int col = n0 + wn * 32 + j * 16 + fr;
            float bv = bias[col];
            #pragma unroll
            for (int q = 0; q < 4; q++) {
                int row = m0 + wm * 32 + i * 16 + kg * 4 + q;
                projb[(long)row * 256 + col] = f2bf(acc[i][j][q] + bv);
            }
        }
}

// ---------------- z-projections: one dispatch, grid (R/64, 3); sel: 0=decay 1=bt 2=ct ----------------
__launch_bounds__(256)
__global__ void mm_z(const short* __restrict__ projb,
                     const float* __restrict__ dtw, const float* __restrict__ dtb,
                     const float* __restrict__ alog,
                     const float* __restrict__ bw, const float* __restrict__ bb_,
                     const float* __restrict__ cw, const float* __restrict__ cb_,
                     float* __restrict__ sdat) {
    __shared__ __align__(16) short As[64][136];
    __shared__ __align__(16) short Ws[64][136];
    const int m0 = blockIdx.x * 64, sel = blockIdx.y;
    const int tid = threadIdx.x;
    const float* W = sel == 0 ? dtw : (sel == 1 ? bw : cw);
    const float* B = sel == 0 ? dtb : (sel == 1 ? bb_ : cb_);

    #pragma unroll
    for (int it = 0; it < 4; ++it) {
        int idx = tid + it * 256;
        int rr = idx >> 4, cc = idx & 15;
        *(bf16x8*)&As[rr][cc * 8] = *(const bf16x8*)&projb[(long)(m0 + rr) * 256 + 128 + cc * 8];
    }
    #pragma unroll
    for (int it = 0; it < 4; ++it) {
        int idx = tid + it * 256;
        int rr = idx >> 4, cc = idx & 15;
        const float* wp = &W[(long)rr * 128 + cc * 8];
        short t8[8];
        #pragma unroll
        for (int q = 0; q < 8; q++) t8[q] = f2bf(wp[q]);
        *(bf16x8*)&Ws[rr][cc * 8] = *(bf16x8*)t8;
    }
    __syncthreads();

    const int wave = tid >> 6, lane = tid & 63;
    const int wm = wave >> 1, wn = wave & 1;
    const int fr = lane & 15, kg = lane >> 4;
    f32x4 acc[2][2];
    #pragma unroll
    for (int i = 0; i < 2; i++)
        #pragma unroll
        for (int j = 0; j < 2; j++) acc[i][j] = (f32x4){0.f, 0.f, 0.f, 0.f};
    #pragma unroll
    for (int ks = 0; ks < 4; ++ks) {
        int kb = ks * 32 + kg * 8;
        bf16x8 a0 = *(const bf16x8*)&As[wm * 32 + fr][kb];
        bf16x8 a1 = *(const bf16x8*)&As[wm * 32 + 16 + fr][kb];
        bf16x8 w0 = *(const bf16x8*)&Ws[wn * 32 + fr][kb];
        bf16x8 w1 = *(const bf16x8*)&Ws[wn * 32 + 16 + fr][kb];
        acc[0][0] = __builtin_amdgcn_mfma_f32_16x16x32_bf16(a0, w0, acc[0][0], 0, 0, 0);
        acc[0][1] = __builtin_amdgcn_mfma_f32_16x16x32_bf16(a0, w1, acc[0][1], 0, 0, 0);
        acc[1][0] = __builtin_amdgcn_mfma_f32_16x16x32_bf16(a1, w0, acc[1][0], 0, 0, 0);
        acc[1][1] = __builtin_amdgcn_mfma_f32_16x16x32_bf16(a1, w1, acc[1][1], 0, 0, 0);
    }
    #pragma unroll
    for (int i = 0; i < 2; i++)
        #pragma unroll
        for (int j = 0; j < 2; j++) {
            int n = wn * 32 + j * 16 + fr;
            float bv = B[n];
            float al = (sel == 0) ? -expf(alog[n]) : 0.f;
            #pragma unroll
            for (int q = 0; q < 4; q++) {
                int row = m0 + wm * 32 + i * 16 + kg * 4 + q;
                float v = acc[i][j][q] + bv;
                if (sel == 0) { float dt = softplus_f(v) + 1e-4f; v = expf(al * dt); }
                else v = tanhf(v);
                sdat[(long)row * 192 + sel * 64 + n] = v;
            }
        }
}

// ---------------- depthwise conv1d(k=3,same)+tanh+*d, wide grid-stride ----------------
__global__ void conv_kernel(const short* __restrict__ projb, const float* __restrict__ cw,
                            const float* __restrict__ cb, const float* __restrict__ dvec,
                            short* __restrict__ mixb, int total) {
    int i = blockIdx.x * blockDim.x + threadIdx.x;
    int stride = gridDim.x * blockDim.x;
    for (; i < total; i += stride) {
        int e = i & 127;
        int r = i >> 7;
        int t = r & (TDIM - 1);
        float x0 = bf2f(projb[(long)r * 256 + e]);
        float xm = (t > 0)        ? bf2f(projb[(long)(r - 1) * 256 + e]) : 0.f;
        float xp = (t < TDIM - 1) ? bf2f(projb[(long)(r + 1) * 256 + e]) : 0.f;
        float v = cw[e * 3 + 0] * xm + cw[e * 3 + 1] * x0 + cw[e * 3 + 2] * xp + cb[e];
        mixb[(long)r * 192 + e] = f2bf(tanhf(v) * dvec[e]);
    }
}

// ---------------- scan phase A: per-chunk affine coefficients (A,B); grid (32,8) x 64 thr ----------------
__global__ void scanA_kernel(const float* __restrict__ sdat, float* __restrict__ chunkAB) {
    int b = blockIdx.x, c = blockIdx.y, s = threadIdx.x;   // 64 threads
    long rbase = (long)b * TDIM + c * 64;
    float A = 1.f, Bc = 0.f;
    #pragma unroll 8
    for (int t = 0; t < 64; ++t) {
        const float* row = sdat + (rbase + t) * 192;
        float d = row[s];
        Bc = Bc * d + row[64 + s];
        A *= d;
    }
    chunkAB[((b * 8 + c) * 2 + 0) * 64 + s] = A;
    chunkAB[((b * 8 + c) * 2 + 1) * 64 + s] = Bc;
}

// ---------------- scan phase C: chunk-prefix fold + rescan; 32 blocks x 512 thr ----------------
__global__ void scanC_kernel(const float* __restrict__ sdat, const float* __restrict__ chunkAB,
                             short* __restrict__ mixb) {
    int b = blockIdx.x, tid = threadIdx.x;   // 512 threads
    int c = tid >> 6, s = tid & 63;
    __shared__ float SI[8][64];
    if (c == 0) {
        float st = 0.f;
        #pragma unroll
        for (int cc = 0; cc < 8; ++cc) {
            SI[cc][s] = st;
            float A = chunkAB[((b * 8 + cc) * 2 + 0) * 64 + s];
            float Bc = chunkAB[((b * 8 + cc) * 2 + 1) * 64 + s];
            st = Bc + A * st;
        }
    }
    __syncthreads();
    long rbase = (long)b * TDIM + c * 64;
    float st = SI[c][s];
    #pragma unroll 4
    for (int t = 0; t < 64; ++t) {
        const float* row = sdat + (rbase + t) * 192;
        st = st * row[s] + row[64 + s];
        mixb[(rbase + t) * 192 + 128 + s] = f2bf(row[128 + s] * st);
    }
}

// ---------------- out-projection + residual (in-place on hseq): K=192 ----------------
__launch_bounds__(256)
__global__ void mm_out(const short* __restrict__ mixb,
                       const float* __restrict__ W, const float* __restrict__ bias,
                       float* __restrict__ hseq) {
    __shared__ __align__(16) short As[64][200];
    __shared__ __align__(16) short Ws[64][200];
    const int m0 = blockIdx.x * 64, n0 = blockIdx.y * 64;
    const int tid = threadIdx.x;

    #pragma unroll
    for (int it = 0; it < 6; ++it) {
        int idx = tid + it * 256;
        int rr = idx / 24, cc = idx % 24;
        *(bf16x8*)&As[rr][cc * 8] = *(const bf16x8*)&mixb[(long)(m0 + rr) * 192 + cc * 8];
    }
    #pragma unroll
    for (int it = 0; it < 6; ++it) {
        int idx = tid + it * 256;
        int rr = idx / 24, cc = idx % 24;
        const float* wp = &W[(long)(n0 + rr) * 192 + cc * 8];
        short t8[8];
        #pragma unroll
        for (int q = 0; q < 8; q++) t8[q] = f2bf(wp[q]);
        *(bf16x8*)&Ws[rr][cc * 8] = *(bf16x8*)t8;
    }
    __syncthreads();

    const int wave = tid >> 6, lane = tid & 63;
    const int wm = wave >> 1, wn = wave & 1;
    const int fr = lane & 15, kg = lane >> 4;
    f32x4 acc[2][2];
    #pragma unroll
    for (int i = 0; i < 2; i++)
        #pragma unroll
        for (int j = 0; j < 2; j++) acc[i][j] = (f32x4){0.f, 0.f, 0.f, 0.f};
    #pragma unroll
    for (int ks = 0; ks < 6; ++ks) {
        int kb = ks * 32 + kg * 8;
        bf16x8 a0 = *(const bf16x8*)&As[wm * 32 + fr][kb];
        bf16x8 a1 = *(const bf16x8*)&As[wm * 32 + 16 + fr][kb];
        bf16x8 w0 = *(const bf16x8*)&Ws[wn * 32 + fr][kb];
        bf16x8 w1 = *(const bf16x8*)&Ws[wn * 32 + 16 + fr][kb];
        acc[0][0] = __builtin_amdgcn_mfma_f32_16x16x32_bf16(a0, w0, acc[0][0], 0, 0, 0);
        acc[0][1] = __builtin_amdgcn_mfma_f32_16x16x32_bf16(a0, w1, acc[0][1], 0, 0, 0);
        acc[1][0] = __builtin_amdgcn_mfma_f32_16x16x32_bf16(a1, w0, acc[1][0], 0, 0, 0);
        acc[1][1] = __builtin_amdgcn_mfma_f32_16x16x32_bf16(a1, w1, acc[1][1], 0, 0, 0);
    }
    #pragma unroll
    for (int i = 0; i < 2; i++)
        #pragma unroll
        for (int j = 0; j < 2; j++) {
            int col = n0 + wn * 32 + j * 16 + fr;
            float bv = bias[col];
            #pragma unroll
            for (int q = 0; q < 4; q++) {
                int row = m0 + wm * 32 + i * 16 + kg * 4 + q;
                hseq[(long)row * 128 + col] += acc[i][j][q] + bv;
            }
        }
}

// ---------------- gx GEMM with fused decoder-embedding gather: gx[4096][480] ----------------
__launch_bounds__(256)
__global__ void mm_gx(const int* __restrict__ resp, const float* __restrict__ table,
                      const int* __restrict__ flags,
                      const float* __restrict__ W, const float* __restrict__ bias,
                      float* __restrict__ gx) {
    __shared__ __align__(16) short As[64][136];
    __shared__ __align__(16) short Ws[64][136];
    const int m0 = blockIdx.x * 64, n0 = blockIdx.y * 64;
    const int tid = threadIdx.x;
    const int mode = flags[2];

    #pragma unroll
    for (int it = 0; it < 4; ++it) {
        int idx = tid + it * 256;
        int rr = idx >> 4, cc = idx & 15;
        int gr = m0 + rr;
        int tk = mode ? resp[2 * gr] : resp[gr];
        const float* sp = &table[(long)tk * 128 + cc * 8];
        short t8[8];
        #pragma unroll
        for (int q = 0; q < 8; q++) t8[q] = f2bf(sp[q]);
        *(bf16x8*)&As[rr][cc * 8] = *(bf16x8*)t8;
    }
    #pragma unroll
    for (int it = 0; it < 4; ++it) {
        int idx = tid + it * 256;
        int rr = idx >> 4, cc = idx & 15;
        int gn = n0 + rr;
        short t8[8];
        if (gn < 480) {
            const float* wp = &W[(long)gn * 128 + cc * 8];
            #pragma unroll
            for (int q = 0; q < 8; q++) t8[q] = f2bf(wp[q]);
        } else {
            #pragma unroll
            for (int q = 0; q < 8; q++) t8[q] = 0;
        }
        *(bf16x8*)&Ws[rr][cc * 8] = *(bf16x8*)t8;
    }
    __syncthreads();

    const int wave = tid >> 6, lane = tid & 63;
    const int wm = wave >> 1, wn = wave & 1;
    const int fr = lane & 15, kg = lane >> 4;
    f32x4 acc[2][2];
    #pragma unroll
    for (int i = 0; i < 2; i++)
        #pragma unroll
        for (int j = 0; j < 2; j++) acc[i][j] = (f32x4){0.f, 0.f, 0.f, 0.f};
    #pragma unroll
    for (int ks = 0; ks < 4; ++ks) {
        int kb = ks * 32 + kg * 8;
        bf16x8 a0 = *(const bf16x8*)&As[wm * 32 + fr][kb];
        bf16x8 a1 = *(const bf16x8*)&As[wm * 32 + 16 + fr][kb];
        bf16x8 w0 = *(const bf16x8*)&Ws[wn * 32 + fr][kb];
        bf16x8 w1 = *(const bf16x8*)&Ws[wn * 32 + 16 + fr][kb];
        acc[0][0] = __builtin_amdgcn_mfma_f32_16x16x32_bf16(a0, w0, acc[0][0], 0, 0, 0);
        acc[0][1] = __builtin_amdgcn_mfma_f32_16x16x32_bf16(a0, w1, acc[0][1], 0, 0, 0);
        acc[1][0] = __builtin_amdgcn_mfma_f32_16x16x32_bf16(a1, w0, acc[1][0], 0, 0, 0);
        acc[1][1] = __builtin_amdgcn_mfma_f32_16x16x32_bf16(a1, w1, acc[1][1], 0, 0, 0);
    }
    #pragma unroll
    for (int i = 0; i < 2; i++)
        #pragma unroll
        for (int j = 0; j < 2; j++) {
            int col = n0 + wn * 32 + j * 16 + fr;
            if (col >= 480) continue;
            float bv = bias[col];
            #pragma unroll
            for (int q = 0; q < 4; q++) {
                int row = m0 + wm * 32 + i * 16 + kg * 4 + q;
                gx[(long)row * 480 + col] = acc[i][j][q] + bv;
            }
        }
}

// ---------------- fused heads + GRU with depth-2 gx register prefetch ----------------
__launch_bounds__(512, 1)
__global__ void gru_heads_kernel(const float* __restrict__ hseq, const int* __restrict__ lengths,
                                 const int* __restrict__ flags,
                                 const float* __restrict__ pg, const float* __restrict__ pb,
                                 const float* __restrict__ sw, const float* __restrict__ sb,
                                 const float* __restrict__ iw_, const float* __restrict__ ib_,
                                 const float* __restrict__ stw, const float* __restrict__ stb,
                                 const float* __restrict__ cw_, const float* __restrict__ cb2,
                                 const float* __restrict__ ow_, const float* __restrict__ ob2,
                                 const float* __restrict__ diw, const float* __restrict__ dib,
                                 const float* __restrict__ gx,
                                 const float* __restrict__ whh, const float* __restrict__ bhh,
                                 float* __restrict__ o_intent, float* __restrict__ o_style,
                                 float* __restrict__ o_cap, float* __restrict__ o_op,
                                 float* __restrict__ o_h,
                                 short* __restrict__ dec_out) {
    int b = blockIdx.x, tid = threadIdx.x;   // 512 threads
    __shared__ float red[4][128];
    __shared__ float pooled[128], hsh[128];
    __shared__ float hs[160], gh[480];
    int lm = flags[1];
    int len = lm ? lengths[2 * b] : lengths[b];
    const float* gxb = gx + (long)b * TDEC * 480;

    // ---- masked mean pool ----
    {
        int e = tid & 127, ch = tid >> 7;
        float s = 0.f;
        for (int t = ch; t < len; t += 4) s += hseq[((long)b * TDIM + t) * 128 + e];
        red[ch][e] = s;
    }
    __syncthreads();
    if (tid < 128) {
        float s = red[0][tid] + red[1][tid] + red[2][tid] + red[3][tid];
        pooled[tid] = s / (float)(len > 1 ? len : 1);
    }
    __syncthreads();
    if (tid < 128) red[0][tid] = pooled[tid];
    __syncthreads();
    for (int off = 64; off > 0; off >>= 1) { if (tid < off) red[0][tid] += red[0][tid + off]; __syncthreads(); }
    float mu = red[0][0] / 128.f;
    __syncthreads();
    if (tid < 128) { float d = pooled[tid] - mu; red[0][tid] = d * d; }
    __syncthreads();
    for (int off = 64; off > 0; off >>= 1) { if (tid < off) red[0][tid] += red[0][tid + off]; __syncthreads(); }
    float rstd = rsqrtf(red[0][0] / 128.f + 1e-5f);
    __syncthreads();
    if (tid < 128) pooled[tid] = (pooled[tid] - mu) * rstd * pg[tid] + pb[tid];
    __syncthreads();
    if (tid < 128) {
        float a = sb[tid];
        for (int k = 0; k < 128; k++) a = fmaf(pooled[k], sw[tid * 128 + k], a);
        a = fmaxf(a, 0.f);
        hsh[tid] = a;
        o_h[b * 128 + tid] = a;
    }
    __syncthreads();
    if (tid < 32) {
        float a = ib_[tid];
        for (int k = 0; k < 128; k++) a = fmaf(hsh[k], iw_[tid * 128 + k], a);
        o_intent[b * 32 + tid] = a;
    } else if (tid < 40) {
        int n = tid - 32; float a = stb[n];
        for (int k = 0; k < 128; k++) a = fmaf(hsh[k], stw[n * 128 + k], a);
        o_style[b * 8 + n] = a;
    } else if (tid < 56) {
        int n = tid - 40; float a = cb2[n];
        for (int k = 0; k < 128; k++) a = fmaf(hsh[k], cw_[n * 128 + k], a);
        o_cap[b * 16 + n] = a;
    } else if (tid < 80) {
        int n = tid - 56; float a = ob2[n];
        for (int k = 0; k < 128; k++) a = fmaf(hsh[k], ow_[n * 128 + k], a);
        o_op[b * 24 + n] = a;
    }
    if (tid < 160) {
        float a = dib[tid];
        for (int k = 0; k < 128; k++) a = fmaf(hsh[k], diw[tid * 128 + k], a);
        hs[tid] = tanhf(a);
    }
    // ---- GRU ----
    f32x4 w[40];
    float bh = 0.f;
    if (tid < 480) {
        bh = bhh[tid];
        const f32x4* wrow = reinterpret_cast<const f32x4*>(whh + tid * 160);
        #pragma unroll
        for (int q = 0; q < 40; q++) w[q] = wrow[q];
    }
    // depth-2 gx prefetch (registers; static indices only)
    float prA = 0.f, pzA = 0.f, pnA = 0.f, prB = 0.f, pzB = 0.f, pnB = 0.f;
    if (tid < 160) {
        prA = gxb[tid];        pzA = gxb[160 + tid];        pnA = gxb[320 + tid];
        prB = gxb[480 + tid];  pzB = gxb[640 + tid];        pnB = gxb[800 + tid];
    }
    __syncthreads();
    for (int t = 0; t < TDEC; ++t) {
        if (tid < 480) {
            const f32x4* hv = reinterpret_cast<const f32x4*>(hs);
            float a0 = bh, a1 = 0.f, a2 = 0.f, a3 = 0.f;
            #pragma unroll
            for (int q = 0; q < 40; q += 4) {
                f32x4 ha = hv[q],     wa = w[q];
                f32x4 hb = hv[q + 1], wb = w[q + 1];
                f32x4 hc = hv[q + 2], wc = w[q + 2];
                f32x4 hd = hv[q + 3], wd = w[q + 3];
                a0 = fmaf(ha.w, wa.w, fmaf(ha.z, wa.z, fmaf(ha.y, wa.y, fmaf(ha.x, wa.x, a0))));
                a1 = fmaf(hb.w, wb.w, fmaf(hb.z, wb.z, fmaf(hb.y, wb.y, fmaf(hb.x, wb.x, a1))));
                a2 = fmaf(hc.w, wc.w, fmaf(hc.z, wc.z, fmaf(hc.y, wc.y, fmaf(hc.x, wc.x, a2))));
                a3 = fmaf(hd.w, wd.w, fmaf(hd.z, wd.z, fmaf(hd.y, wd.y, fmaf(hd.x, wd.x, a3))));
            }
            gh[tid] = (a0 + a1) + (a2 + a3);
        }
        __syncthreads();
        if (tid < 160) {
            float r = sigmoid_f(prA + gh[tid]);
            float z = sigmoid_f(pzA + gh[160 + tid]);
            float n = tanhf(pnA + r * gh[320 + tid]);
            float hnew = (1.f - z) * n + z * hs[tid];
            dec_out[((long)b * TDEC + t) * 160 + tid] = f2bf(hnew);
            hs[tid] = hnew;
            // rotate prefetch pipeline; issue loads for t+2 (complete over next 2 phases)
            prA = prB; pzA = pzB; pnA = pnB;
            if (t + 2 < TDEC) {
                const float* g2 = gxb + (long)(t + 2) * 480;
                prB = g2[tid]; pzB = g2[160 + tid]; pnB = g2[320 + tid];
            }
        }
        __syncthreads();
    }
}

// ---------------- vocab projection: bf16 MFMA, coalesced f32x4 epilogue via LDS ----------------
__launch_bounds__(256)
__global__ void vocab_gemm(const short* __restrict__ A,
                           const short* __restrict__ W,
                           const float* __restrict__ bias,
                           float* __restrict__ C) {
    __shared__ __align__(16) short As[128][168];
    __shared__ __align__(16) short Ws[64][168];
    int n0 = blockIdx.x * 64, m0 = blockIdx.y * 128;
    int tid = threadIdx.x;

    #pragma unroll
    for (int it = 0; it < 10; ++it) {
        int idx = tid + it * 256;
        int r = idx / 20, c8 = idx % 20;
        *(bf16x8*)&As[r][c8 * 8] = *(const bf16x8*)&A[(long)(m0 + r) * 160 + c8 * 8];
    }
    #pragma unroll
    for (int it = 0; it < 5; ++it) {
        int idx = tid + it * 256;
        int r = idx / 20, c8 = idx % 20;
        *(bf16x8*)&Ws[r][c8 * 8] = *(const bf16x8*)&W[(long)(n0 + r) * 160 + c8 * 8];
    }
    __syncthreads();

    int wave = tid >> 6, lane = tid & 63;
    int wm = wave >> 1, wn = wave & 1;
    int fr = lane & 15, kg = lane >> 4;

    f32x4 acc[4][2];
    #pragma unroll
    for (int i = 0; i < 4; i++)
        #pragma unroll
        for (int j = 0; j < 2; j++) acc[i][j] = (f32x4){0.f, 0.f, 0.f, 0.f};

    #pragma unroll
    for (int ks = 0; ks < 5; ++ks) {
        int kb = ks * 32 + kg * 8;
        bf16x8 a[4], bfr[2];
        #pragma unroll
        for (int i = 0; i < 4; i++)
            a[i] = *(const bf16x8*)&As[wm * 64 + i * 16 + fr][kb];
        #pragma unroll
        for (int j = 0; j < 2; j++)
            bfr[j] = *(const bf16x8*)&Ws[wn * 32 + j * 16 + fr][kb];
        #pragma unroll
        for (int i = 0; i < 4; i++)
            #pragma unroll
            for (int j = 0; j < 2; j++)
                acc[i][j] = __builtin_amdgcn_mfma_f32_16x16x32_bf16(a[i], bfr[j], acc[i][j], 0, 0, 0);
    }

    __syncthreads();
    float* Cs = (float*)&As[0][0];   // [128][64]
    #pragma unroll
    for (int i = 0; i < 4; i++)
        #pragma unroll
        for (int j = 0; j < 2; j++) {
            int col = wn * 32 + j * 16 + fr;
            #pragma unroll
            for (int q = 0; q < 4; q++) {
                int row = wm * 64 + i * 16 + kg * 4 + q;
                Cs[row * 64 + col] = acc[i][j][q];
            }
        }
    __syncthreads();
    #pragma unroll
    for (int it = 0; it < 8; ++it) {
        int idx = tid + it * 256;
        int row = idx >> 4, c4 = (idx & 15) * 4;
        f32x4 v = *(f32x4*)&Cs[row * 64 + c4];
        int gc = n0 + c4;
        v.x += bias[gc]; v.y += bias[gc + 1]; v.z += bias[gc + 2]; v.w += bias[gc + 3];
        *(f32x4*)&C[(long)(m0 + row) * VOCAB + gc] = v;
    }
}

extern "C" void kernel_launch(void* const* d_in, const int* in_sizes, int n_in,
                              void* d_out, int out_size, void* d_ws, size_t ws_size,
                              hipStream_t stream) {
    const int* x        = (const int*)d_in[0];
    const int* lengths  = (const int*)d_in[1];
    const int* resp_in  = (const int*)d_in[2];
    const float* emb_table = (const float*)d_in[3];
    const float* m_norm_g  = (const float*)d_in[4];
    const float* m_norm_b  = (const float*)d_in[5];
    const float* m_in_w    = (const float*)d_in[6];
    const float* m_in_b    = (const float*)d_in[7];
    const float* m_conv_w  = (const float*)d_in[8];
    const float* m_conv_b  = (const float*)d_in[9];
    const float* m_dt_w    = (const float*)d_in[10];
    const float* m_dt_b    = (const float*)d_in[11];
    const float* m_b_w     = (const float*)d_in[12];
    const float* m_b_b     = (const float*)d_in[13];
    const float* m_c_w     = (const float*)d_in[14];
    const float* m_c_b     = (const float*)d_in[15];
    const float* m_a_log   = (const float*)d_in[16];
    const float* m_d       = (const float*)d_in[17];
    const float* m_out_w   = (const float*)d_in[18];
    const float* m_out_b   = (const float*)d_in[19];
    const float* pool_g    = (const float*)d_in[20];
    const float* pool_b    = (const float*)d_in[21];
    const float* shared_w  = (const float*)d_in[22];
    const float* shared_b  = (const float*)d_in[23];
    const float* intent_w  = (const float*)d_in[24];
    const float* intent_b  = (const float*)d_in[25];
    const float* style_w   = (const float*)d_in[26];
    const float* style_b   = (const float*)d_in[27];
    const float* cap_w     = (const float*)d_in[28];
    const float* cap_b     = (const float*)d_in[29];
    const float* op_w      = (const float*)d_in[30];
    const float* op_b      = (const float*)d_in[31];
    const float* dec_emb   = (const float*)d_in[32];
    const float* dec_init_w = (const float*)d_in[33];
    const float* dec_init_b = (const float*)d_in[34];
    const float* gru_w_ih  = (const float*)d_in[35];
    const float* gru_w_hh  = (const float*)d_in[36];
    const float* gru_b_ih  = (const float*)d_in[37];
    const float* gru_b_hh  = (const float*)d_in[38];
    const float* dec_out_w = (const float*)d_in[39];
    const float* dec_out_b = (const float*)d_in[40];

    float* out = (float*)d_out;
    const long o_intent = 0;
    const long o_style  = 32 * 32;
    const long o_cap    = o_style + 32 * 8;
    const long o_op     = o_cap + 32 * 16;
    const long o_logits = o_op + 32 * 24;
    const long o_h      = o_logits + (long)BDIM * TDEC * VOCAB;

    const int R = BDIM * TDIM;                 // 16384
    const int Rd = BDIM * TDEC;                // 4096

    // large scratch inside d_out logits region (524 MB capacity, ~44 MB used);
    // vocab_gemm is the final dispatch and fully overwrites this region.
    char* Sb = (char*)(out + o_logits);
    float* hseq  = (float*)Sb;  Sb += (long)R * 128 * 4;
    short* projb = (short*)Sb;  Sb += (long)R * 256 * 2;
    float* sdat  = (float*)Sb;  Sb += (long)R * 192 * 4;
    short* mixb  = (short*)Sb;  Sb += (long)R * 192 * 2;
    float* gx    = (float*)Sb;  Sb += (long)Rd * 480 * 4;

    // d_ws (~11.8 MB, prior rounds prove >=11.6 MB available)
    int* flags   = (int*)d_ws;
    short* dec_obf = (short*)((float*)d_ws + 16);           // [4096][160] bf16
    short* w_bf  = dec_obf + (long)Rd * HID;                // [32000][160] bf16
    float* chunkAB = (float*)(w_bf + (long)VOCAB * HID);    // [32][8][2][64] f32 = 131 KB

    prep_kernel<<<2048, 256, 0, stream>>>(dec_out_w, w_bf, VOCAB * HID, x, lengths, resp_in, flags);
    embed_kernel<<<4096, 256, 0, stream>>>(x, emb_table, hseq, R * 128, flags, 0);

    for (int i = 0; i < 2; ++i) {
        mm_inproj<<<dim3(R / 64, 4), 256, 0, stream>>>(
            hseq, m_norm_g + i * 128, m_norm_b + i * 128,
            m_in_w + i * 256 * 128, m_in_b + i * 256, projb);
        mm_z<<<dim3(R / 64, 3), 256, 0, stream>>>(
            projb, m_dt_w + i * 8192, m_dt_b + i * 64, m_a_log + i * 64,
            m_b_w + i * 8192, m_b_b + i * 64,
            m_c_w + i * 8192, m_c_b + i * 64, sdat);
        conv_kernel<<<2048, 256, 0, stream>>>(
            projb, m_conv_w + i * 384, m_conv_b + i * 128, m_d + i * 128, mixb, R * 128);
        scanA_kernel<<<dim3(BDIM, 8), 64, 0, stream>>>(sdat, chunkAB);
        scanC_kernel<<<BDIM, 512, 0, stream>>>(sdat, chunkAB, mixb);
        mm_out<<<dim3(R / 64, 2), 256, 0, stream>>>(
            mixb, m_out_w + i * 128 * 192, m_out_b + i * 128, hseq);
    }

    mm_gx<<<dim3(Rd / 64, 8), 256, 0, stream>>>(
        resp_in, dec_emb, flags, gru_w_ih, gru_b_ih, gx);
    gru_heads_kernel<<<BDIM, 512, 0, stream>>>(
        hseq, lengths, flags,
        pool_g, pool_b, shared_w, shared_b,
        intent_w, intent_b, style_w, style_b, cap_w, cap_b, op_w, op_b,
        dec_init_w, dec_init_b,
        gx, gru_w_hh, gru_b_hh,
        out + o_intent, out + o_style, out + o_cap, out + o_op, out + o_h,
        dec_obf);
    vocab_gemm<<<dim3(VOCAB / 64, Rd / 128), 256, 0, stream>>>(
        dec_obf, w_bf, dec_out_b, out + o_logits);
}